// Round 12
// baseline (109.013 us; speedup 1.0000x reference)
//
#include <hip/hip_runtime.h>
#include <math.h>

// Problem constants
#define NB 8      // batch
#define NC 256    // channels
#define NN 1024   // spatial H*W
#define NICH 64   // inter channels

// ws layout (float offsets)
#define WS_AQ    0        // [256]
#define WS_AK    256      // [256]
#define WS_MOM2  520      // [8][4]: Seq,Sek,Sek2,Sekq per batch
#define WS_SX    1024     // [8][256]
#define WS_XE    3072     // [8][256]
#define WS_XK    5120     // [8][256]
#define WS_T1P   7424     // [64]
#define WS_T2P   7488     // [64]
#define WS_VSU   7680     // [8][256]
#define WS_UE    9728     // [8][256]
#define WS_VEU   11776    // [8][256]
#define WS_CAQ   13824    // [8][256]
#define WS_CAK   15872    // [8][256]
#define WS_CUAK  17920    // [8][256]
#define WS_STAT  20480    // [8] stride 2560: (ek, Sv, Sve used)
#define STAT_STRIDE 2560
#define ST_EK    1024
#define ST_SV    2048
#define ST_SVE   2304
#define WS_EQP2  57344    // [16][1024] depth-2 partials (b*2+ch)
#define WS_EKP2  73728    // [16][1024]
#define WS_MAQP2 90112    // [16][1024]
#define WS_MAKP2 106496   // [16][1024]
#define WS_SX2P  123904   // [256]
#define WS_UUP   124160   // [256]

__device__ __forceinline__ float dot4(const float4& a, const float4& b) {
    return a.x * b.x + a.y * b.y + a.z * b.z + a.w * b.w;
}
__device__ __forceinline__ float sum4(const float4& a) {
    return a.x + a.y + a.z + a.w;
}
__device__ __forceinline__ unsigned int bf16lo(float v) {
    unsigned int u = __float_as_uint(v);
    return (u + 0x7FFFu + ((u >> 16) & 1u)) >> 16;
}
__device__ __forceinline__ unsigned int bf16hi(float v) {
    unsigned int u = __float_as_uint(v);
    return (u + 0x7FFFu + ((u >> 16) & 1u)) & 0xFFFF0000u;
}
__device__ __forceinline__ float tolo(unsigned int u) {
    return __uint_as_float(u << 16);
}
__device__ __forceinline__ float tohi(unsigned int u) {
    return __uint_as_float(u & 0xFFFF0000u);
}

// kA: depth-2 partials of eq/ek/maq/mak. 256 blocks = (b, nq in 16, ch-half).
__global__ void kA(const float* __restrict__ x, const float* __restrict__ u,
                   const float* __restrict__ Wq, const float* __restrict__ Wk,
                   const float* __restrict__ Wc, float* __restrict__ ws) {
    const int bid = blockIdx.x;
    const int b = bid >> 5, r = bid & 31;
    const int nq = r >> 1, ch = r & 1;
    const int t = threadIdx.x;   // 256
    __shared__ float aql[128], akl[128];
    __shared__ float red[4][4][64];
    {
        const int c_local = t >> 1, half = t & 1;
        const int cg = ch * 128 + c_local;
        float a = 0.f, k = 0.f;
#pragma unroll 8
        for (int i = 0; i < 32; ++i) {
            int o = half * 32 + i;
            a += Wc[o] * Wq[o * NC + cg];
            k += Wc[64 + o] * Wk[o * NC + cg];
        }
        a += __shfl_xor(a, 1, 64);
        k += __shfl_xor(k, 1, 64);
        if (half == 0) {
            aql[c_local] = a; akl[c_local] = k;
            if (nq == 0) { ws[WS_AQ + cg] = a; ws[WS_AK + cg] = k; }
        }
    }
    __syncthreads();
    const int col = t & 63, grp = t >> 6;
    const int n = nq * 64 + col;
    const float* xb = x + ((size_t)b * NC + ch * 128 + grp * 32) * NN + n;
    const float* ub = u + ((size_t)b * NC + ch * 128 + grp * 32) * NN + n;
    float eqp = 0.f, ekp = 0.f, map = 0.f, mkp = 0.f;
#pragma unroll 8
    for (int i = 0; i < 32; ++i) {
        float xv = xb[(size_t)i * NN];
        float uv = ub[(size_t)i * NN];
        float a = aql[grp * 32 + i], kk = akl[grp * 32 + i];
        eqp += a * xv; ekp += kk * xv;
        map += a * uv; mkp += kk * uv;
    }
    red[grp][0][col] = eqp; red[grp][1][col] = ekp;
    red[grp][2][col] = map; red[grp][3][col] = mkp;
    __syncthreads();
    if (t < 64) {
        int idx = (b * 2 + ch) * 1024 + nq * 64 + t;
        ws[WS_EQP2  + idx] = red[0][0][t] + red[1][0][t] + red[2][0][t] + red[3][0][t];
        ws[WS_EKP2  + idx] = red[0][1][t] + red[1][1][t] + red[2][1][t] + red[3][1][t];
        ws[WS_MAQP2 + idx] = red[0][2][t] + red[1][2][t] + red[2][2][t] + red[3][2][t];
        ws[WS_MAKP2 + idx] = red[0][3][t] + red[1][3][t] + red[2][3][t] + red[3][3][t];
    }
}

// kB: finalize eq/ek/maq/mak (2 partials in-register), moments, row-dots.
__global__ void kB(const float* __restrict__ x, const float* __restrict__ u,
                   const float* __restrict__ Wc, const float* __restrict__ bq,
                   const float* __restrict__ bk, float* __restrict__ ws) {
    const int bid = blockIdx.x;
    const int b = bid >> 5, g = bid & 31;
    const int c0 = g * 8;
    const int t = threadIdx.x;   // 256
    const int wid = t >> 6, lane = t & 63;
    __shared__ float s_cq, s_ck;
    __shared__ float mred[4][4];
    __shared__ float wv9[8][9][4];
    __shared__ float accw[2][4];
    if (t < 64) {
        float p = Wc[t] * bq[t], rr = Wc[64 + t] * bk[t];
        for (int off = 32; off > 0; off >>= 1) {
            p += __shfl_down(p, off, 64);
            rr += __shfl_down(rr, off, 64);
        }
        if (t == 0) { s_cq = p; s_ck = rr; }
    }
    __syncthreads();
    const float cq = s_cq, ck = s_ck;
    float4 e4, k4, ma4, mk4;
    {
        float4 a0 = ((const float4*)(ws + WS_EQP2 + (size_t)(b * 2) * 1024))[t];
        float4 a1 = ((const float4*)(ws + WS_EQP2 + (size_t)(b * 2 + 1) * 1024))[t];
        e4.x = a0.x + a1.x + cq; e4.y = a0.y + a1.y + cq;
        e4.z = a0.z + a1.z + cq; e4.w = a0.w + a1.w + cq;
        a0 = ((const float4*)(ws + WS_EKP2 + (size_t)(b * 2) * 1024))[t];
        a1 = ((const float4*)(ws + WS_EKP2 + (size_t)(b * 2 + 1) * 1024))[t];
        k4.x = a0.x + a1.x + ck; k4.y = a0.y + a1.y + ck;
        k4.z = a0.z + a1.z + ck; k4.w = a0.w + a1.w + ck;
        a0 = ((const float4*)(ws + WS_MAQP2 + (size_t)(b * 2) * 1024))[t];
        a1 = ((const float4*)(ws + WS_MAQP2 + (size_t)(b * 2 + 1) * 1024))[t];
        ma4.x = a0.x + a1.x; ma4.y = a0.y + a1.y; ma4.z = a0.z + a1.z; ma4.w = a0.w + a1.w;
        a0 = ((const float4*)(ws + WS_MAKP2 + (size_t)(b * 2) * 1024))[t];
        a1 = ((const float4*)(ws + WS_MAKP2 + (size_t)(b * 2 + 1) * 1024))[t];
        mk4.x = a0.x + a1.x; mk4.y = a0.y + a1.y; mk4.z = a0.z + a1.z; mk4.w = a0.w + a1.w;
    }
    {
        float d0 = sum4(e4), d1 = sum4(k4), d2 = dot4(k4, k4), d3 = dot4(e4, k4);
        for (int off = 32; off > 0; off >>= 1) {
            d0 += __shfl_down(d0, off, 64);
            d1 += __shfl_down(d1, off, 64);
            d2 += __shfl_down(d2, off, 64);
            d3 += __shfl_down(d3, off, 64);
        }
        if (lane == 0) { mred[0][wid] = d0; mred[1][wid] = d1; mred[2][wid] = d2; mred[3][wid] = d3; }
    }
    __syncthreads();
    if (t == 0)
        for (int m = 0; m < 4; ++m)
            ws[WS_MOM2 + b * 4 + m] = mred[m][0] + mred[m][1] + mred[m][2] + mred[m][3];
    if (g == 0)
        ((float4*)(ws + WS_STAT + b * STAT_STRIDE + ST_EK))[t] = k4;
    const float4* xb4 = (const float4*)(x + ((size_t)b * NC + c0) * NN);
    const float4* ub4 = (const float4*)(u + ((size_t)b * NC + c0) * NN);
    float x2a = 0.f, uua = 0.f;
#pragma unroll
    for (int c = 0; c < 8; ++c) {
        float4 xv = xb4[c * 256 + t];
        float4 uv = ub4[c * 256 + t];
        float d[9];
        d[0] = dot4(xv, e4);   // xe
        d[1] = dot4(xv, k4);   // xk
        d[2] = sum4(uv);       // Vsu
        d[3] = dot4(uv, e4);   // Ue
        d[4] = dot4(uv, k4);   // Veu
        d[5] = dot4(xv, ma4);  // caq
        d[6] = dot4(xv, mk4);  // cak
        d[7] = dot4(uv, mk4);  // cuak
        d[8] = sum4(xv);       // sx
        x2a += dot4(xv, xv);
        uua += dot4(uv, uv);
        for (int off = 32; off > 0; off >>= 1)
            for (int m = 0; m < 9; ++m) d[m] += __shfl_down(d[m], off, 64);
        if (lane == 0) for (int m = 0; m < 9; ++m) wv9[c][m][wid] = d[m];
    }
    for (int off = 32; off > 0; off >>= 1) {
        x2a += __shfl_down(x2a, off, 64);
        uua += __shfl_down(uua, off, 64);
    }
    if (lane == 0) { accw[0][wid] = x2a; accw[1][wid] = uua; }
    __syncthreads();
    if (t < 8) {
        int c = t;
        float v[9];
        for (int m = 0; m < 9; ++m)
            v[m] = wv9[c][m][0] + wv9[c][m][1] + wv9[c][m][2] + wv9[c][m][3];
        ws[WS_XE   + b * NC + c0 + c] = v[0];
        ws[WS_XK   + b * NC + c0 + c] = v[1];
        ws[WS_VSU  + b * NC + c0 + c] = v[2];
        ws[WS_UE   + b * NC + c0 + c] = v[3];
        ws[WS_VEU  + b * NC + c0 + c] = v[4];
        ws[WS_CAQ  + b * NC + c0 + c] = v[5];
        ws[WS_CAK  + b * NC + c0 + c] = v[6];
        ws[WS_CUAK + b * NC + c0 + c] = v[7];
        ws[WS_SX   + b * NC + c0 + c] = v[8];
    }
    if (t == 0) {
        ws[WS_SX2P + bid] = accw[0][0] + accw[0][1] + accw[0][2] + accw[0][3];
        ws[WS_UUP + bid]  = accw[1][0] + accw[1][1] + accw[1][2] + accw[1][3];
    }
}

// ksv: Sv/Sve matvec + per-block T1/T2 partials for d2
__global__ void ksv(const float* __restrict__ Wv, const float* __restrict__ bv,
                    const float* __restrict__ Wc, const float* __restrict__ bq,
                    const float* __restrict__ bk, float* __restrict__ ws) {
    const int bid = blockIdx.x;          // 64: b*8 + oc
    const int b = bid >> 3, oc = bid & 7;
    const int t = threadIdx.x;           // 256
    const int o_sub = t >> 3, ks = t & 7;
    const int o = oc * 32 + o_sub;
    __shared__ float sxl[NC], xel[NC];
    __shared__ float T1s[32], T2s[32];
    __shared__ float s_cq, s_ck;
    if (t < 64) {
        float p = Wc[t] * bq[t], rr = Wc[64 + t] * bk[t];
        for (int off = 32; off > 0; off >>= 1) {
            p += __shfl_down(p, off, 64);
            rr += __shfl_down(rr, off, 64);
        }
        if (t == 0) { s_cq = p; s_ck = rr; }
    }
    sxl[t] = ws[WS_SX + b * NC + t];
    xel[t] = ws[WS_XE + b * NC + t];
    __syncthreads();
    const float Seq  = ws[WS_MOM2 + b * 4 + 0];
    const float Sek  = ws[WS_MOM2 + b * 4 + 1];
    const float Sek2 = ws[WS_MOM2 + b * 4 + 2];
    const float cq = s_cq, ck = s_ck;
    float wsx = 0.f, wxe = 0.f;
    const float4* wrow = (const float4*)(Wv + (size_t)o * NC);
#pragma unroll
    for (int i = 0; i < 8; ++i) {
        float4 w4 = wrow[i * 8 + ks];
        int k = i * 32 + ks * 4;
        wsx += w4.x * sxl[k] + w4.y * sxl[k + 1] + w4.z * sxl[k + 2] + w4.w * sxl[k + 3];
        wxe += w4.x * xel[k] + w4.y * xel[k + 1] + w4.z * xel[k + 2] + w4.w * xel[k + 3];
    }
    for (int off = 4; off > 0; off >>= 1) {
        wsx += __shfl_down(wsx, off, 8);
        wxe += __shfl_down(wxe, off, 8);
    }
    if (ks == 0) {
        float bvc = bv[o];
        float Sv  = wsx + (float)NN * bvc;
        float SvL = wsx;
        float Sve = wxe + bvc * Seq;
        float* st = ws + WS_STAT + b * STAT_STRIDE;
        st[ST_SV + o] = Sv; st[ST_SVE + o] = Sve;
        float A = 2.f * Sve - bvc * Seq - cq * Sv;
        float sx = sxl[o];
        float xk = ws[WS_XK + b * NC + o];
        float xkL = xk - ck * sx;
        float T1c = A * sx + Sv * xkL + SvL * xk;
        float SP  = Sek - (float)NN * ck;
        float SP2 = Sek2 - 2.f * ck * Sek + (float)NN * ck * ck;
        float SPQ = Sek2 - ck * Sek;
        float T2c = (float)NN * A * A + Sv * Sv * SP2 + SvL * SvL * Sek2
                  + 2.f * A * Sv * SP + 2.f * A * SvL * Sek + 2.f * Sv * SvL * SPQ;
        T1s[o_sub] = T1c; T2s[o_sub] = T2c;
    }
    __syncthreads();
    if (t == 0) {
        float t1 = 0.f, t2 = 0.f;
        for (int i = 0; i < 32; ++i) { t1 += T1s[i]; t2 += T2s[i]; }
        ws[WS_T1P + bid] = t1;
        ws[WS_T2P + bid] = t2;
    }
}

// kiter: 5-term vjp/trace recursion. W quarter-rows in per-thread REGISTERS
// (32 packed-bf16 u32); Vs/Ve packed bf16 in LDS (VVb) -> per iter only 16
// uniform b128 LDS reads/thread (round-10's 64 LDS ops/thread/iter were the
// ~35us LDS-pipe bottleneck).
__global__ void kiter(const float* __restrict__ Wv, const float* __restrict__ bv,
                      const float* __restrict__ gamma, float* __restrict__ ws,
                      float* __restrict__ out) {
    const int b = blockIdx.x;            // 8
    const int t = threadIdx.x;           // 1024
    const int o = t & 255, q = t >> 8;
    const int wid4 = o >> 6, lane = t & 63;
    __shared__ unsigned int VVb[NC];
    __shared__ float redPR[2 * 1024];
    __shared__ float dred[9][4];
    __shared__ float gred0[4], gredT[2];
    __shared__ float sge;
    // W quarter-row -> registers (coalesced global loads; L2/L3-resident)
    unsigned int wreg[32];
#pragma unroll 8
    for (int i = 0; i < 32; ++i) {
        float w0 = Wv[(size_t)(q * 64 + 2 * i) * NC + o];
        float w1 = Wv[(size_t)(q * 64 + 2 * i + 1) * NC + o];
        wreg[i] = bf16lo(w0) | bf16hi(w1);
    }
    // gamma_eff
    {
        float a = 0.f, b1 = 0.f, c1 = 0.f;
        if (t < 256) a = ws[WS_SX2P + t];
        if (t < 64) { b1 = ws[WS_T1P + t]; c1 = ws[WS_T2P + t]; }
        for (int off = 32; off > 0; off >>= 1) {
            a  += __shfl_down(a,  off, 64);
            b1 += __shfl_down(b1, off, 64);
            c1 += __shfl_down(c1, off, 64);
        }
        if (t < 256 && lane == 0) gred0[t >> 6] = a;
        if (t == 0) { gredT[0] = b1; gredT[1] = c1; }
    }
    __syncthreads();
    if (t == 0) {
        float S1 = gred0[0] + gred0[1] + gred0[2] + gred0[3];
        float inv = gamma[0] * (1.f / (float)NN);
        float dd = S1 + 2.f * inv * gredT[0] + inv * inv * gredT[1];
        float lip = sqrtf(dd / S1);
        sge = gamma[0] * ((lip > 0.9f) ? (0.9f / lip) : 1.f);
    }
    __syncthreads();
    const float s = sge * (1.f / (float)NN);
    // per-channel constants (t<256)
    float Svl_r = 0.f, sxl_r = 0.f, xkl_r = 0.f, caql_r = 0.f, cakl_r = 0.f,
          Uel_r = 0.f, Vsul_r = 0.f, bvl_r = 0.f, aql_r = 0.f, akl_r = 0.f,
          veu_r = 0.f, cuak_r = 0.f, vsreg = 0.f, vereg = 0.f;
    if (t < 256) {
        const float* st = ws + WS_STAT + b * STAT_STRIDE;
        Svl_r  = st[ST_SV + t];
        sxl_r  = ws[WS_SX   + b * NC + t];
        xkl_r  = ws[WS_XK   + b * NC + t];
        caql_r = ws[WS_CAQ  + b * NC + t];
        cakl_r = ws[WS_CAK  + b * NC + t];
        Uel_r  = ws[WS_UE   + b * NC + t];
        Vsul_r = ws[WS_VSU  + b * NC + t];
        veu_r  = ws[WS_VEU  + b * NC + t];
        cuak_r = ws[WS_CUAK + b * NC + t];
        aql_r  = ws[WS_AQ + t];
        akl_r  = ws[WS_AK + t];
        bvl_r  = bv[t];
        vsreg = Vsul_r; vereg = veu_r;
        VVb[t] = bf16lo(vsreg) | bf16hi(vereg);
    }
    const float Seq  = ws[WS_MOM2 + b * 4 + 0];
    const float Sek  = ws[WS_MOM2 + b * 4 + 1];
    const float Sekq = ws[WS_MOM2 + b * 4 + 3];
    float uu = 0.f;
    for (int g = 0; g < 32; ++g) uu += ws[WS_UUP + b * 32 + g];
    __syncthreads();
    // prologue dots
    if (t < 256) {
        float d[8] = {Svl_r * cuak_r, aql_r * Vsul_r, akl_r * Vsul_r, akl_r * Uel_r,
                      Svl_r * Vsul_r, Svl_r * veu_r,  Svl_r * aql_r,  Svl_r * akl_r};
        for (int off = 32; off > 0; off >>= 1)
            for (int m = 0; m < 8; ++m) d[m] += __shfl_down(d[m], off, 64);
        if (lane == 0) for (int m = 0; m < 8; ++m) dred[m][wid4] = d[m];
    }
    __syncthreads();
    float g2a = 0.f, aqVsu = 0.f, akVsu = 0.f, akUe = 0.f, SvVsu = 0.f, SvVeu = 0.f,
          Svaq = 0.f, Svak = 0.f;
    if (t < 256) {
        g2a   = dred[0][0] + dred[0][1] + dred[0][2] + dred[0][3];
        aqVsu = dred[1][0] + dred[1][1] + dred[1][2] + dred[1][3];
        akVsu = dred[2][0] + dred[2][1] + dred[2][2] + dred[2][3];
        akUe  = dred[3][0] + dred[3][1] + dred[3][2] + dred[3][3];
        SvVsu = dred[4][0] + dred[4][1] + dred[4][2] + dred[4][3];
        SvVeu = dred[5][0] + dred[5][1] + dred[5][2] + dred[5][3];
        Svaq  = dred[6][0] + dred[6][1] + dred[6][2] + dred[6][3];
        Svak  = dred[7][0] + dred[7][1] + dred[7][2] + dred[7][3];
    }
    __syncthreads();
    const float lam = 1.f + s * Svak;
    float alpha = 1.f, beta = 0.f, gam = 0.f;
    float SxAcc = 0.f, XkAcc = 0.f, CakAcc = 0.f;
    float dot = uu, tr = 0.f;
    const float coef[5] = {1.f, -0.5f, 1.f / 3.f, -0.25f, 0.2f};
    for (int j = 0; j < 5; ++j) {
        // matvec: W from registers, VVb (bf16-packed Vs/Ve) uniform b128 reads
        float pa = 0.f, ra = 0.f;
#pragma unroll
        for (int k = 0; k < 16; ++k) {
            uint4 v4 = ((const uint4*)VVb)[q * 16 + k];
            unsigned int w01 = wreg[2 * k], w23 = wreg[2 * k + 1];
            pa += tolo(w01) * tolo(v4.x); ra += tolo(w01) * tohi(v4.x);
            pa += tohi(w01) * tolo(v4.y); ra += tohi(w01) * tohi(v4.y);
            pa += tolo(w23) * tolo(v4.z); ra += tolo(w23) * tohi(v4.z);
            pa += tohi(w23) * tolo(v4.w); ra += tohi(w23) * tohi(v4.w);
        }
        redPR[2 * t] = pa; redPR[2 * t + 1] = ra;
        __syncthreads();
        if (t < 256) {
            float Pv = s * (redPR[2 * t] + redPR[2 * (t + 256)] + redPR[2 * (t + 512)] + redPR[2 * (t + 768)]);
            float Rv = s * (redPR[2 * t + 1] + redPR[2 * (t + 256) + 1] + redPR[2 * (t + 512) + 1] + redPR[2 * (t + 768) + 1]);
            redPR[2 * t] = Pv; redPR[2 * t + 1] = Rv;  // stash for phase 2
            float d[9];
            d[0] = Svl_r * Pv;
            d[1] = Svl_r * Rv;
            d[2] = bvl_r * vsreg;
            d[3] = sxl_r * Pv;
            d[4] = xkl_r * Pv;
            d[5] = caql_r * Pv;
            d[6] = cakl_r * Pv;
            d[7] = Uel_r * Pv;
            d[8] = Vsul_r * Rv;
            for (int off = 32; off > 0; off >>= 1)
                for (int m = 0; m < 9; ++m) d[m] += __shfl_down(d[m], off, 64);
            if (lane == 0) for (int m = 0; m < 9; ++m) dred[m][wid4] = d[m];
        }
        __syncthreads();
        if (t < 256) {
            float Pv = redPR[2 * t], Rv = redPR[2 * t + 1];
            float sm[9];
            for (int m = 0; m < 9; ++m)
                sm[m] = dred[m][0] + dred[m][1] + dred[m][2] + dred[m][3];
            const float svP = sm[0], svR = sm[1], bvVs = sm[2], sxP = sm[3], xkP = sm[4],
                        caqP = sm[5], cakP = sm[6], ueP = sm[7], vsuR = sm[8];
            const float sB = s * bvVs;
            float St  = s * (alpha * SvVsu + beta * (float)NN + gam * Seq  + Svaq * SxAcc);
            float tek = s * (alpha * SvVeu + beta * Sek        + gam * Sekq + Svaq * XkAcc);
            float uta = s * (alpha * g2a   + beta * akVsu      + gam * akUe + Svaq * CakAcc);
            dot += ueP + caqP + sB * aqVsu + uta + vsuR;
            tr  += coef[j] * dot;
            float nVs = vsreg + Pv * Seq  + aql_r * (sxP + (float)NN * sB) + akl_r * St  + Rv * (float)NN;
            float nVe = vereg + Pv * Sekq + aql_r * (xkP + sB * Sek)       + akl_r * tek + Rv * Sek;
            vsreg = nVs; vereg = nVe;
            VVb[t] = bf16lo(nVs) | bf16hi(nVe);
            SxAcc  = lam * SxAcc  + sxP;
            XkAcc  = lam * XkAcc  + xkP;
            CakAcc = lam * CakAcc + cakP;
            beta = lam * beta + Svaq * sB + svR;
            gam  = lam * gam + svP;
            alpha *= lam;
        }
        __syncthreads();
    }
    if (t == 0) out[2097152 + b] = tr;
}

// kout0: 2048 blocks x 256; ge computed per block from partials.
__global__ void kout0(const float* __restrict__ x, const float* __restrict__ gamma,
                      const float* __restrict__ ws, float* __restrict__ out) {
    int bid = blockIdx.x;            // 2048: b*256 + c
    int b = bid >> 8, c = bid & 255, t = threadIdx.x;  // 256
    const int wid = t >> 6, lane = t & 63;
    __shared__ float g0[4], gT[2];
    __shared__ float sge;
    {
        float a = ws[WS_SX2P + t];
        float b1 = 0.f, c1 = 0.f;
        if (t < 64) { b1 = ws[WS_T1P + t]; c1 = ws[WS_T2P + t]; }
        for (int off = 32; off > 0; off >>= 1) {
            a  += __shfl_down(a,  off, 64);
            b1 += __shfl_down(b1, off, 64);
            c1 += __shfl_down(c1, off, 64);
        }
        if (lane == 0) g0[wid] = a;
        if (t == 0) { gT[0] = b1; gT[1] = c1; }
    }
    __syncthreads();
    if (t == 0) {
        float S1 = g0[0] + g0[1] + g0[2] + g0[3];
        float inv = gamma[0] * (1.f / (float)NN);
        float dd = S1 + 2.f * inv * gT[0] + inv * inv * gT[1];
        float lip = sqrtf(dd / S1);
        sge = gamma[0] * ((lip > 0.9f) ? (0.9f / lip) : 1.f);
    }
    __syncthreads();
    float ge = sge * (1.f / (float)NN);
    const float* st = ws + WS_STAT + b * STAT_STRIDE;
    float sv = st[ST_SV + c], sve = st[ST_SVE + c];
    float4 ek4 = ((const float4*)(st + ST_EK))[t];
    size_t i4 = (size_t)bid * 256 + t;
    float4 x4 = ((const float4*)x)[i4];
    float4 o;
    o.x = 2.f * x4.x + ge * (sve + ek4.x * sv);
    o.y = 2.f * x4.y + ge * (sve + ek4.y * sv);
    o.z = 2.f * x4.z + ge * (sve + ek4.z * sv);
    o.w = 2.f * x4.w + ge * (sve + ek4.w * sv);
    ((float4*)out)[i4] = o;
}

extern "C" void kernel_launch(void* const* d_in, const int* in_sizes, int n_in,
                              void* d_out, int out_size, void* d_ws, size_t ws_size,
                              hipStream_t stream) {
    const float* x     = (const float*)d_in[0];
    const float* Wq    = (const float*)d_in[1];
    const float* bq    = (const float*)d_in[2];
    const float* Wk    = (const float*)d_in[3];
    const float* bk    = (const float*)d_in[4];
    const float* Wc    = (const float*)d_in[5];
    const float* Wv    = (const float*)d_in[6];
    const float* bv    = (const float*)d_in[7];
    const float* gamma = (const float*)d_in[8];
    const float* u     = (const float*)d_in[9];
    float* out = (float*)d_out;
    float* ws  = (float*)d_ws;

    kA   <<<dim3(256),  dim3(256),  0, stream>>>(x, u, Wq, Wk, Wc, ws);
    kB   <<<dim3(256),  dim3(256),  0, stream>>>(x, u, Wc, bq, bk, ws);
    ksv  <<<dim3(64),   dim3(256),  0, stream>>>(Wv, bv, Wc, bq, bk, ws);
    kiter<<<dim3(8),    dim3(1024), 0, stream>>>(Wv, bv, gamma, ws, out);
    kout0<<<dim3(2048), dim3(256),  0, stream>>>(x, gamma, ws, out);
}

// Round 13
// 65.926 us; speedup vs baseline: 1.6536x; 1.6536x over previous
//
#include <hip/hip_runtime.h>
#include <math.h>

// Problem constants
#define NB 8      // batch
#define NC 256    // channels
#define NN 1024   // spatial H*W
#define NICH 64   // inter channels

// ws layout (float offsets)
#define WS_AQ    0        // [256]
#define WS_AK    256      // [256]
#define WS_MOM2  520      // [8][4]: Seq,Sek,Sek2,Sekq per batch
#define WS_SX    1024     // [8][256]
#define WS_XE    3072     // [8][256]
#define WS_XK    5120     // [8][256]
#define WS_T1P   7424     // [64]
#define WS_T2P   7488     // [64]
#define WS_VSU   7680     // [8][256]
#define WS_UE    9728     // [8][256]
#define WS_VEU   11776    // [8][256]
#define WS_CAQ   13824    // [8][256]
#define WS_CAK   15872    // [8][256]
#define WS_CUAK  17920    // [8][256]
#define WS_STAT  20480    // [8] stride 2560: (ek, Sv, Sve used)
#define STAT_STRIDE 2560
#define ST_EK    1024
#define ST_SV    2048
#define ST_SVE   2304
#define WS_EQP2  57344    // [16][1024] depth-2 partials (b*2+ch)
#define WS_EKP2  73728    // [16][1024]
#define WS_MAQP2 90112    // [16][1024]
#define WS_MAKP2 106496   // [16][1024]
#define WS_SX2P  123904   // [256]
#define WS_UUP   124160   // [256]
#define WS_WVB   124416   // [32768] u32: packed bf16 Wv pairs, kiter layout

__device__ __forceinline__ float dot4(const float4& a, const float4& b) {
    return a.x * b.x + a.y * b.y + a.z * b.z + a.w * b.w;
}
__device__ __forceinline__ float sum4(const float4& a) {
    return a.x + a.y + a.z + a.w;
}
__device__ __forceinline__ unsigned int bf16lo(float v) {
    unsigned int u = __float_as_uint(v);
    return (u + 0x7FFFu + ((u >> 16) & 1u)) >> 16;
}
__device__ __forceinline__ unsigned int bf16hi(float v) {
    unsigned int u = __float_as_uint(v);
    return (u + 0x7FFFu + ((u >> 16) & 1u)) & 0xFFFF0000u;
}
__device__ __forceinline__ float tolo(unsigned int u) {
    return __uint_as_float(u << 16);
}
__device__ __forceinline__ float tohi(unsigned int u) {
    return __uint_as_float(u & 0xFFFF0000u);
}

// kA: depth-2 partials of eq/ek/maq/mak (blocks 0..255) + Wv bf16-pack
// conversion (blocks 256..287, wide & coalesced — removes kiter's f32
// staging + conversion entirely).
__global__ void kA(const float* __restrict__ x, const float* __restrict__ u,
                   const float* __restrict__ Wq, const float* __restrict__ Wk,
                   const float* __restrict__ Wc, const float* __restrict__ Wv,
                   float* __restrict__ ws) {
    const int bid = blockIdx.x;
    const int t = threadIdx.x;   // 256
    if (bid >= 256) {
        // WVB[(q*32+i)*256+o] = pack(Wv[q*64+2i][o], Wv[q*64+2i+1][o])
        const int j = bid - 256;   // 0..31
        unsigned int* wvb = (unsigned int*)ws + WS_WVB;
#pragma unroll
        for (int r = 0; r < 4; ++r) {
            int e = j * 1024 + r * 256 + t;
            int q = e >> 13, i = (e >> 8) & 31, o = e & 255;
            float w0 = Wv[(size_t)(q * 64 + 2 * i) * NC + o];
            float w1 = Wv[(size_t)(q * 64 + 2 * i + 1) * NC + o];
            wvb[e] = bf16lo(w0) | bf16hi(w1);
        }
        return;
    }
    const int b = bid >> 5, r = bid & 31;
    const int nq = r >> 1, ch = r & 1;
    __shared__ float aql[128], akl[128];
    __shared__ float red[4][4][64];
    {
        const int c_local = t >> 1, half = t & 1;
        const int cg = ch * 128 + c_local;
        float a = 0.f, k = 0.f;
#pragma unroll 8
        for (int i = 0; i < 32; ++i) {
            int o = half * 32 + i;
            a += Wc[o] * Wq[o * NC + cg];
            k += Wc[64 + o] * Wk[o * NC + cg];
        }
        a += __shfl_xor(a, 1, 64);
        k += __shfl_xor(k, 1, 64);
        if (half == 0) {
            aql[c_local] = a; akl[c_local] = k;
            if (nq == 0) { ws[WS_AQ + cg] = a; ws[WS_AK + cg] = k; }
        }
    }
    __syncthreads();
    const int col = t & 63, grp = t >> 6;
    const int n = nq * 64 + col;
    const float* xb = x + ((size_t)b * NC + ch * 128 + grp * 32) * NN + n;
    const float* ub = u + ((size_t)b * NC + ch * 128 + grp * 32) * NN + n;
    float eqp = 0.f, ekp = 0.f, map = 0.f, mkp = 0.f;
#pragma unroll 8
    for (int i = 0; i < 32; ++i) {
        float xv = xb[(size_t)i * NN];
        float uv = ub[(size_t)i * NN];
        float a = aql[grp * 32 + i], kk = akl[grp * 32 + i];
        eqp += a * xv; ekp += kk * xv;
        map += a * uv; mkp += kk * uv;
    }
    red[grp][0][col] = eqp; red[grp][1][col] = ekp;
    red[grp][2][col] = map; red[grp][3][col] = mkp;
    __syncthreads();
    if (t < 64) {
        int idx = (b * 2 + ch) * 1024 + nq * 64 + t;
        ws[WS_EQP2  + idx] = red[0][0][t] + red[1][0][t] + red[2][0][t] + red[3][0][t];
        ws[WS_EKP2  + idx] = red[0][1][t] + red[1][1][t] + red[2][1][t] + red[3][1][t];
        ws[WS_MAQP2 + idx] = red[0][2][t] + red[1][2][t] + red[2][2][t] + red[3][2][t];
        ws[WS_MAKP2 + idx] = red[0][3][t] + red[1][3][t] + red[2][3][t] + red[3][3][t];
    }
}

// kB: finalize eq/ek/maq/mak (2 partials in-register), moments, row-dots.
__global__ void kB(const float* __restrict__ x, const float* __restrict__ u,
                   const float* __restrict__ Wc, const float* __restrict__ bq,
                   const float* __restrict__ bk, float* __restrict__ ws) {
    const int bid = blockIdx.x;
    const int b = bid >> 5, g = bid & 31;
    const int c0 = g * 8;
    const int t = threadIdx.x;   // 256
    const int wid = t >> 6, lane = t & 63;
    __shared__ float s_cq, s_ck;
    __shared__ float mred[4][4];
    __shared__ float wv9[8][9][4];
    __shared__ float accw[2][4];
    if (t < 64) {
        float p = Wc[t] * bq[t], rr = Wc[64 + t] * bk[t];
        for (int off = 32; off > 0; off >>= 1) {
            p += __shfl_down(p, off, 64);
            rr += __shfl_down(rr, off, 64);
        }
        if (t == 0) { s_cq = p; s_ck = rr; }
    }
    __syncthreads();
    const float cq = s_cq, ck = s_ck;
    float4 e4, k4, ma4, mk4;
    {
        float4 a0 = ((const float4*)(ws + WS_EQP2 + (size_t)(b * 2) * 1024))[t];
        float4 a1 = ((const float4*)(ws + WS_EQP2 + (size_t)(b * 2 + 1) * 1024))[t];
        e4.x = a0.x + a1.x + cq; e4.y = a0.y + a1.y + cq;
        e4.z = a0.z + a1.z + cq; e4.w = a0.w + a1.w + cq;
        a0 = ((const float4*)(ws + WS_EKP2 + (size_t)(b * 2) * 1024))[t];
        a1 = ((const float4*)(ws + WS_EKP2 + (size_t)(b * 2 + 1) * 1024))[t];
        k4.x = a0.x + a1.x + ck; k4.y = a0.y + a1.y + ck;
        k4.z = a0.z + a1.z + ck; k4.w = a0.w + a1.w + ck;
        a0 = ((const float4*)(ws + WS_MAQP2 + (size_t)(b * 2) * 1024))[t];
        a1 = ((const float4*)(ws + WS_MAQP2 + (size_t)(b * 2 + 1) * 1024))[t];
        ma4.x = a0.x + a1.x; ma4.y = a0.y + a1.y; ma4.z = a0.z + a1.z; ma4.w = a0.w + a1.w;
        a0 = ((const float4*)(ws + WS_MAKP2 + (size_t)(b * 2) * 1024))[t];
        a1 = ((const float4*)(ws + WS_MAKP2 + (size_t)(b * 2 + 1) * 1024))[t];
        mk4.x = a0.x + a1.x; mk4.y = a0.y + a1.y; mk4.z = a0.z + a1.z; mk4.w = a0.w + a1.w;
    }
    {
        float d0 = sum4(e4), d1 = sum4(k4), d2 = dot4(k4, k4), d3 = dot4(e4, k4);
        for (int off = 32; off > 0; off >>= 1) {
            d0 += __shfl_down(d0, off, 64);
            d1 += __shfl_down(d1, off, 64);
            d2 += __shfl_down(d2, off, 64);
            d3 += __shfl_down(d3, off, 64);
        }
        if (lane == 0) { mred[0][wid] = d0; mred[1][wid] = d1; mred[2][wid] = d2; mred[3][wid] = d3; }
    }
    __syncthreads();
    if (t == 0)
        for (int m = 0; m < 4; ++m)
            ws[WS_MOM2 + b * 4 + m] = mred[m][0] + mred[m][1] + mred[m][2] + mred[m][3];
    if (g == 0)
        ((float4*)(ws + WS_STAT + b * STAT_STRIDE + ST_EK))[t] = k4;
    const float4* xb4 = (const float4*)(x + ((size_t)b * NC + c0) * NN);
    const float4* ub4 = (const float4*)(u + ((size_t)b * NC + c0) * NN);
    float x2a = 0.f, uua = 0.f;
#pragma unroll
    for (int c = 0; c < 8; ++c) {
        float4 xv = xb4[c * 256 + t];
        float4 uv = ub4[c * 256 + t];
        float d[9];
        d[0] = dot4(xv, e4);   // xe
        d[1] = dot4(xv, k4);   // xk
        d[2] = sum4(uv);       // Vsu
        d[3] = dot4(uv, e4);   // Ue
        d[4] = dot4(uv, k4);   // Veu
        d[5] = dot4(xv, ma4);  // caq
        d[6] = dot4(xv, mk4);  // cak
        d[7] = dot4(uv, mk4);  // cuak
        d[8] = sum4(xv);       // sx
        x2a += dot4(xv, xv);
        uua += dot4(uv, uv);
        for (int off = 32; off > 0; off >>= 1)
            for (int m = 0; m < 9; ++m) d[m] += __shfl_down(d[m], off, 64);
        if (lane == 0) for (int m = 0; m < 9; ++m) wv9[c][m][wid] = d[m];
    }
    for (int off = 32; off > 0; off >>= 1) {
        x2a += __shfl_down(x2a, off, 64);
        uua += __shfl_down(uua, off, 64);
    }
    if (lane == 0) { accw[0][wid] = x2a; accw[1][wid] = uua; }
    __syncthreads();
    if (t < 8) {
        int c = t;
        float v[9];
        for (int m = 0; m < 9; ++m)
            v[m] = wv9[c][m][0] + wv9[c][m][1] + wv9[c][m][2] + wv9[c][m][3];
        ws[WS_XE   + b * NC + c0 + c] = v[0];
        ws[WS_XK   + b * NC + c0 + c] = v[1];
        ws[WS_VSU  + b * NC + c0 + c] = v[2];
        ws[WS_UE   + b * NC + c0 + c] = v[3];
        ws[WS_VEU  + b * NC + c0 + c] = v[4];
        ws[WS_CAQ  + b * NC + c0 + c] = v[5];
        ws[WS_CAK  + b * NC + c0 + c] = v[6];
        ws[WS_CUAK + b * NC + c0 + c] = v[7];
        ws[WS_SX   + b * NC + c0 + c] = v[8];
    }
    if (t == 0) {
        ws[WS_SX2P + bid] = accw[0][0] + accw[0][1] + accw[0][2] + accw[0][3];
        ws[WS_UUP + bid]  = accw[1][0] + accw[1][1] + accw[1][2] + accw[1][3];
    }
}

// ksv: Sv/Sve matvec + per-block T1/T2 partials for d2
__global__ void ksv(const float* __restrict__ Wv, const float* __restrict__ bv,
                    const float* __restrict__ Wc, const float* __restrict__ bq,
                    const float* __restrict__ bk, float* __restrict__ ws) {
    const int bid = blockIdx.x;          // 64: b*8 + oc
    const int b = bid >> 3, oc = bid & 7;
    const int t = threadIdx.x;           // 256
    const int o_sub = t >> 3, ks = t & 7;
    const int o = oc * 32 + o_sub;
    __shared__ float sxl[NC], xel[NC];
    __shared__ float T1s[32], T2s[32];
    __shared__ float s_cq, s_ck;
    if (t < 64) {
        float p = Wc[t] * bq[t], rr = Wc[64 + t] * bk[t];
        for (int off = 32; off > 0; off >>= 1) {
            p += __shfl_down(p, off, 64);
            rr += __shfl_down(rr, off, 64);
        }
        if (t == 0) { s_cq = p; s_ck = rr; }
    }
    sxl[t] = ws[WS_SX + b * NC + t];
    xel[t] = ws[WS_XE + b * NC + t];
    __syncthreads();
    const float Seq  = ws[WS_MOM2 + b * 4 + 0];
    const float Sek  = ws[WS_MOM2 + b * 4 + 1];
    const float Sek2 = ws[WS_MOM2 + b * 4 + 2];
    const float cq = s_cq, ck = s_ck;
    float wsx = 0.f, wxe = 0.f;
    const float4* wrow = (const float4*)(Wv + (size_t)o * NC);
#pragma unroll
    for (int i = 0; i < 8; ++i) {
        float4 w4 = wrow[i * 8 + ks];
        int k = i * 32 + ks * 4;
        wsx += w4.x * sxl[k] + w4.y * sxl[k + 1] + w4.z * sxl[k + 2] + w4.w * sxl[k + 3];
        wxe += w4.x * xel[k] + w4.y * xel[k + 1] + w4.z * xel[k + 2] + w4.w * xel[k + 3];
    }
    for (int off = 4; off > 0; off >>= 1) {
        wsx += __shfl_down(wsx, off, 8);
        wxe += __shfl_down(wxe, off, 8);
    }
    if (ks == 0) {
        float bvc = bv[o];
        float Sv  = wsx + (float)NN * bvc;
        float SvL = wsx;
        float Sve = wxe + bvc * Seq;
        float* st = ws + WS_STAT + b * STAT_STRIDE;
        st[ST_SV + o] = Sv; st[ST_SVE + o] = Sve;
        float A = 2.f * Sve - bvc * Seq - cq * Sv;
        float sx = sxl[o];
        float xk = ws[WS_XK + b * NC + o];
        float xkL = xk - ck * sx;
        float T1c = A * sx + Sv * xkL + SvL * xk;
        float SP  = Sek - (float)NN * ck;
        float SP2 = Sek2 - 2.f * ck * Sek + (float)NN * ck * ck;
        float SPQ = Sek2 - ck * Sek;
        float T2c = (float)NN * A * A + Sv * Sv * SP2 + SvL * SvL * Sek2
                  + 2.f * A * Sv * SP + 2.f * A * SvL * Sek + 2.f * Sv * SvL * SPQ;
        T1s[o_sub] = T1c; T2s[o_sub] = T2c;
    }
    __syncthreads();
    if (t == 0) {
        float t1 = 0.f, t2 = 0.f;
        for (int i = 0; i < 32; ++i) { t1 += T1s[i]; t2 += T2s[i]; }
        ws[WS_T1P + bid] = t1;
        ws[WS_T2P + bid] = t2;
    }
}

// kiter: 5-term vjp/trace recursion. Wv arrives PRE-PACKED bf16 (WVB, written
// wide by kA) -> staging is a pure linear uint4 copy (8 loads + 8 b128 LDS
// writes per thread, max MLP, no conversion, no register array to spill).
// Matvec: Wlds b32 reads (2 lanes/bank = conflict-free) + uniform uint2 VVb.
__global__ void kiter(const float* __restrict__ bv,
                      const float* __restrict__ gamma, float* __restrict__ ws,
                      float* __restrict__ out) {
    const int b = blockIdx.x;            // 8
    const int t = threadIdx.x;           // 1024
    const int o = t & 255, q = t >> 8;
    const int wid4 = o >> 6, lane = t & 63;
    __shared__ unsigned int Wlds[32768];     // 128KB packed bf16 pairs
    __shared__ __align__(16) unsigned int VVb[NC];
    __shared__ float redPR[2 * 1024];
    __shared__ float dred[9][4];
    __shared__ float gred0[4], gredT[2];
    __shared__ float sge;
    // stage WVB -> LDS (linear copy)
    {
        const uint4* wvb4 = (const uint4*)((const unsigned int*)ws + WS_WVB);
        uint4 stg[8];
#pragma unroll
        for (int k2 = 0; k2 < 8; ++k2) stg[k2] = wvb4[k2 * 1024 + t];
#pragma unroll
        for (int k2 = 0; k2 < 8; ++k2) ((uint4*)Wlds)[k2 * 1024 + t] = stg[k2];
    }
    // gamma_eff
    {
        float a = 0.f, b1 = 0.f, c1 = 0.f;
        if (t < 256) a = ws[WS_SX2P + t];
        if (t < 64) { b1 = ws[WS_T1P + t]; c1 = ws[WS_T2P + t]; }
        for (int off = 32; off > 0; off >>= 1) {
            a  += __shfl_down(a,  off, 64);
            b1 += __shfl_down(b1, off, 64);
            c1 += __shfl_down(c1, off, 64);
        }
        if (t < 256 && lane == 0) gred0[t >> 6] = a;
        if (t == 0) { gredT[0] = b1; gredT[1] = c1; }
    }
    __syncthreads();
    if (t == 0) {
        float S1 = gred0[0] + gred0[1] + gred0[2] + gred0[3];
        float inv = gamma[0] * (1.f / (float)NN);
        float dd = S1 + 2.f * inv * gredT[0] + inv * inv * gredT[1];
        float lip = sqrtf(dd / S1);
        sge = gamma[0] * ((lip > 0.9f) ? (0.9f / lip) : 1.f);
    }
    __syncthreads();
    const float s = sge * (1.f / (float)NN);
    // per-channel constants (t<256)
    float Svl_r = 0.f, sxl_r = 0.f, xkl_r = 0.f, caql_r = 0.f, cakl_r = 0.f,
          Uel_r = 0.f, Vsul_r = 0.f, bvl_r = 0.f, aql_r = 0.f, akl_r = 0.f,
          veu_r = 0.f, cuak_r = 0.f, vsreg = 0.f, vereg = 0.f;
    if (t < 256) {
        const float* st = ws + WS_STAT + b * STAT_STRIDE;
        Svl_r  = st[ST_SV + t];
        sxl_r  = ws[WS_SX   + b * NC + t];
        xkl_r  = ws[WS_XK   + b * NC + t];
        caql_r = ws[WS_CAQ  + b * NC + t];
        cakl_r = ws[WS_CAK  + b * NC + t];
        Uel_r  = ws[WS_UE   + b * NC + t];
        Vsul_r = ws[WS_VSU  + b * NC + t];
        veu_r  = ws[WS_VEU  + b * NC + t];
        cuak_r = ws[WS_CUAK + b * NC + t];
        aql_r  = ws[WS_AQ + t];
        akl_r  = ws[WS_AK + t];
        bvl_r  = bv[t];
        vsreg = Vsul_r; vereg = veu_r;
        VVb[t] = bf16lo(vsreg) | bf16hi(vereg);
    }
    const float Seq  = ws[WS_MOM2 + b * 4 + 0];
    const float Sek  = ws[WS_MOM2 + b * 4 + 1];
    const float Sekq = ws[WS_MOM2 + b * 4 + 3];
    float uu = 0.f;
    for (int g = 0; g < 32; ++g) uu += ws[WS_UUP + b * 32 + g];
    __syncthreads();
    // prologue dots
    if (t < 256) {
        float d[8] = {Svl_r * cuak_r, aql_r * Vsul_r, akl_r * Vsul_r, akl_r * Uel_r,
                      Svl_r * Vsul_r, Svl_r * veu_r,  Svl_r * aql_r,  Svl_r * akl_r};
        for (int off = 32; off > 0; off >>= 1)
            for (int m = 0; m < 8; ++m) d[m] += __shfl_down(d[m], off, 64);
        if (lane == 0) for (int m = 0; m < 8; ++m) dred[m][wid4] = d[m];
    }
    __syncthreads();
    float g2a = 0.f, aqVsu = 0.f, akVsu = 0.f, akUe = 0.f, SvVsu = 0.f, SvVeu = 0.f,
          Svaq = 0.f, Svak = 0.f;
    if (t < 256) {
        g2a   = dred[0][0] + dred[0][1] + dred[0][2] + dred[0][3];
        aqVsu = dred[1][0] + dred[1][1] + dred[1][2] + dred[1][3];
        akVsu = dred[2][0] + dred[2][1] + dred[2][2] + dred[2][3];
        akUe  = dred[3][0] + dred[3][1] + dred[3][2] + dred[3][3];
        SvVsu = dred[4][0] + dred[4][1] + dred[4][2] + dred[4][3];
        SvVeu = dred[5][0] + dred[5][1] + dred[5][2] + dred[5][3];
        Svaq  = dred[6][0] + dred[6][1] + dred[6][2] + dred[6][3];
        Svak  = dred[7][0] + dred[7][1] + dred[7][2] + dred[7][3];
    }
    __syncthreads();
    const float lam = 1.f + s * Svak;
    float alpha = 1.f, beta = 0.f, gam = 0.f;
    float SxAcc = 0.f, XkAcc = 0.f, CakAcc = 0.f;
    float dot = uu, tr = 0.f;
    const float coef[5] = {1.f, -0.5f, 1.f / 3.f, -0.25f, 0.2f};
    for (int j = 0; j < 5; ++j) {
        // matvec: Wlds b32 (conflict-free) x VVb uniform uint2 broadcast
        float pa = 0.f, ra = 0.f;
#pragma unroll
        for (int ii = 0; ii < 32; ++ii) {
            unsigned int w = Wlds[(q * 32 + ii) * 256 + o];
            uint2 v2 = ((const uint2*)VVb)[q * 32 + ii];
            float wlo = tolo(w), whi = tohi(w);
            pa += wlo * tolo(v2.x) + whi * tolo(v2.y);
            ra += wlo * tohi(v2.x) + whi * tohi(v2.y);
        }
        redPR[2 * t] = pa; redPR[2 * t + 1] = ra;
        __syncthreads();
        if (t < 256) {
            float Pv = s * (redPR[2 * t] + redPR[2 * (t + 256)] + redPR[2 * (t + 512)] + redPR[2 * (t + 768)]);
            float Rv = s * (redPR[2 * t + 1] + redPR[2 * (t + 256) + 1] + redPR[2 * (t + 512) + 1] + redPR[2 * (t + 768) + 1]);
            redPR[2 * t] = Pv; redPR[2 * t + 1] = Rv;  // stash for phase 2
            float d[9];
            d[0] = Svl_r * Pv;
            d[1] = Svl_r * Rv;
            d[2] = bvl_r * vsreg;
            d[3] = sxl_r * Pv;
            d[4] = xkl_r * Pv;
            d[5] = caql_r * Pv;
            d[6] = cakl_r * Pv;
            d[7] = Uel_r * Pv;
            d[8] = Vsul_r * Rv;
            for (int off = 32; off > 0; off >>= 1)
                for (int m = 0; m < 9; ++m) d[m] += __shfl_down(d[m], off, 64);
            if (lane == 0) for (int m = 0; m < 9; ++m) dred[m][wid4] = d[m];
        }
        __syncthreads();
        if (t < 256) {
            float Pv = redPR[2 * t], Rv = redPR[2 * t + 1];
            float sm[9];
            for (int m = 0; m < 9; ++m)
                sm[m] = dred[m][0] + dred[m][1] + dred[m][2] + dred[m][3];
            const float svP = sm[0], svR = sm[1], bvVs = sm[2], sxP = sm[3], xkP = sm[4],
                        caqP = sm[5], cakP = sm[6], ueP = sm[7], vsuR = sm[8];
            const float sB = s * bvVs;
            float St  = s * (alpha * SvVsu + beta * (float)NN + gam * Seq  + Svaq * SxAcc);
            float tek = s * (alpha * SvVeu + beta * Sek        + gam * Sekq + Svaq * XkAcc);
            float uta = s * (alpha * g2a   + beta * akVsu      + gam * akUe + Svaq * CakAcc);
            dot += ueP + caqP + sB * aqVsu + uta + vsuR;
            tr  += coef[j] * dot;
            float nVs = vsreg + Pv * Seq  + aql_r * (sxP + (float)NN * sB) + akl_r * St  + Rv * (float)NN;
            float nVe = vereg + Pv * Sekq + aql_r * (xkP + sB * Sek)       + akl_r * tek + Rv * Sek;
            vsreg = nVs; vereg = nVe;
            VVb[t] = bf16lo(nVs) | bf16hi(nVe);
            SxAcc  = lam * SxAcc  + sxP;
            XkAcc  = lam * XkAcc  + xkP;
            CakAcc = lam * CakAcc + cakP;
            beta = lam * beta + Svaq * sB + svR;
            gam  = lam * gam + svP;
            alpha *= lam;
        }
        __syncthreads();
    }
    if (t == 0) out[2097152 + b] = tr;
}

// kout0: 2048 blocks x 256; ge computed per block from partials.
__global__ void kout0(const float* __restrict__ x, const float* __restrict__ gamma,
                      const float* __restrict__ ws, float* __restrict__ out) {
    int bid = blockIdx.x;            // 2048: b*256 + c
    int b = bid >> 8, c = bid & 255, t = threadIdx.x;  // 256
    const int wid = t >> 6, lane = t & 63;
    __shared__ float g0[4], gT[2];
    __shared__ float sge;
    {
        float a = ws[WS_SX2P + t];
        float b1 = 0.f, c1 = 0.f;
        if (t < 64) { b1 = ws[WS_T1P + t]; c1 = ws[WS_T2P + t]; }
        for (int off = 32; off > 0; off >>= 1) {
            a  += __shfl_down(a,  off, 64);
            b1 += __shfl_down(b1, off, 64);
            c1 += __shfl_down(c1, off, 64);
        }
        if (lane == 0) g0[wid] = a;
        if (t == 0) { gT[0] = b1; gT[1] = c1; }
    }
    __syncthreads();
    if (t == 0) {
        float S1 = g0[0] + g0[1] + g0[2] + g0[3];
        float inv = gamma[0] * (1.f / (float)NN);
        float dd = S1 + 2.f * inv * gT[0] + inv * inv * gT[1];
        float lip = sqrtf(dd / S1);
        sge = gamma[0] * ((lip > 0.9f) ? (0.9f / lip) : 1.f);
    }
    __syncthreads();
    float ge = sge * (1.f / (float)NN);
    const float* st = ws + WS_STAT + b * STAT_STRIDE;
    float sv = st[ST_SV + c], sve = st[ST_SVE + c];
    float4 ek4 = ((const float4*)(st + ST_EK))[t];
    size_t i4 = (size_t)bid * 256 + t;
    float4 x4 = ((const float4*)x)[i4];
    float4 o;
    o.x = 2.f * x4.x + ge * (sve + ek4.x * sv);
    o.y = 2.f * x4.y + ge * (sve + ek4.y * sv);
    o.z = 2.f * x4.z + ge * (sve + ek4.z * sv);
    o.w = 2.f * x4.w + ge * (sve + ek4.w * sv);
    ((float4*)out)[i4] = o;
}

extern "C" void kernel_launch(void* const* d_in, const int* in_sizes, int n_in,
                              void* d_out, int out_size, void* d_ws, size_t ws_size,
                              hipStream_t stream) {
    const float* x     = (const float*)d_in[0];
    const float* Wq    = (const float*)d_in[1];
    const float* bq    = (const float*)d_in[2];
    const float* Wk    = (const float*)d_in[3];
    const float* bk    = (const float*)d_in[4];
    const float* Wc    = (const float*)d_in[5];
    const float* Wv    = (const float*)d_in[6];
    const float* bv    = (const float*)d_in[7];
    const float* gamma = (const float*)d_in[8];
    const float* u     = (const float*)d_in[9];
    float* out = (float*)d_out;
    float* ws  = (float*)d_ws;

    kA   <<<dim3(288),  dim3(256),  0, stream>>>(x, u, Wq, Wk, Wc, Wv, ws);
    kB   <<<dim3(256),  dim3(256),  0, stream>>>(x, u, Wc, bq, bk, ws);
    ksv  <<<dim3(64),   dim3(256),  0, stream>>>(Wv, bv, Wc, bq, bk, ws);
    kiter<<<dim3(8),    dim3(1024), 0, stream>>>(bv, gamma, ws, out);
    kout0<<<dim3(2048), dim3(256),  0, stream>>>(x, gamma, ws, out);
}

// Round 14
// 55.479 us; speedup vs baseline: 1.9649x; 1.1883x over previous
//
#include <hip/hip_runtime.h>
#include <math.h>

// Problem constants
#define NB 8      // batch
#define NC 256    // channels
#define NN 1024   // spatial H*W
#define NICH 64   // inter channels

// ws layout (float offsets)
#define WS_AQ    0        // [256]
#define WS_AK    256      // [256]
#define WS_MOM2  520      // [8][4]: Seq,Sek,Sek2,Sekq per batch
#define WS_SX    1024     // [8][256]
#define WS_XE    3072     // [8][256]
#define WS_XK    5120     // [8][256]
#define WS_T1P   7424     // [64]
#define WS_T2P   7488     // [64]
#define WS_VSU   7680     // [8][256]
#define WS_UE    9728     // [8][256]
#define WS_VEU   11776    // [8][256]
#define WS_CAQ   13824    // [8][256]
#define WS_CAK   15872    // [8][256]
#define WS_CUAK  17920    // [8][256]
#define WS_STAT  20480    // [8] stride 2560: (ek, Sv, Sve used)
#define STAT_STRIDE 2560
#define ST_EK    1024
#define ST_SV    2048
#define ST_SVE   2304
#define WS_EQP2  57344    // [16][1024] depth-2 partials (b*2+ch)
#define WS_EKP2  73728    // [16][1024]
#define WS_MAQP2 90112    // [16][1024]
#define WS_MAKP2 106496   // [16][1024]
#define WS_SX2P  123904   // [256]
#define WS_UUP   124160   // [256]
#define WS_WVB   124416   // [32768] u32: packed bf16 Wv pairs, kiter layout

__device__ __forceinline__ float dot4(const float4& a, const float4& b) {
    return a.x * b.x + a.y * b.y + a.z * b.z + a.w * b.w;
}
__device__ __forceinline__ float sum4(const float4& a) {
    return a.x + a.y + a.z + a.w;
}
__device__ __forceinline__ unsigned int bf16lo(float v) {
    unsigned int u = __float_as_uint(v);
    return (u + 0x7FFFu + ((u >> 16) & 1u)) >> 16;
}
__device__ __forceinline__ unsigned int bf16hi(float v) {
    unsigned int u = __float_as_uint(v);
    return (u + 0x7FFFu + ((u >> 16) & 1u)) & 0xFFFF0000u;
}
__device__ __forceinline__ float tolo(unsigned int u) {
    return __uint_as_float(u << 16);
}
__device__ __forceinline__ float tohi(unsigned int u) {
    return __uint_as_float(u & 0xFFFF0000u);
}

// kA: depth-2 partials of eq/ek/maq/mak (blocks 0..255) + Wv bf16-pack
// conversion (blocks 256..287, wide & coalesced).
__global__ void kA(const float* __restrict__ x, const float* __restrict__ u,
                   const float* __restrict__ Wq, const float* __restrict__ Wk,
                   const float* __restrict__ Wc, const float* __restrict__ Wv,
                   float* __restrict__ ws) {
    const int bid = blockIdx.x;
    const int t = threadIdx.x;   // 256
    if (bid >= 256) {
        const int j = bid - 256;   // 0..31
        unsigned int* wvb = (unsigned int*)ws + WS_WVB;
#pragma unroll
        for (int r = 0; r < 4; ++r) {
            int e = j * 1024 + r * 256 + t;
            int q = e >> 13, i = (e >> 8) & 31, o = e & 255;
            float w0 = Wv[(size_t)(q * 64 + 2 * i) * NC + o];
            float w1 = Wv[(size_t)(q * 64 + 2 * i + 1) * NC + o];
            wvb[e] = bf16lo(w0) | bf16hi(w1);
        }
        return;
    }
    const int b = bid >> 5, r = bid & 31;
    const int nq = r >> 1, ch = r & 1;
    __shared__ float aql[128], akl[128];
    __shared__ float red[4][4][64];
    {
        const int c_local = t >> 1, half = t & 1;
        const int cg = ch * 128 + c_local;
        float a = 0.f, k = 0.f;
#pragma unroll 8
        for (int i = 0; i < 32; ++i) {
            int o = half * 32 + i;
            a += Wc[o] * Wq[o * NC + cg];
            k += Wc[64 + o] * Wk[o * NC + cg];
        }
        a += __shfl_xor(a, 1, 64);
        k += __shfl_xor(k, 1, 64);
        if (half == 0) {
            aql[c_local] = a; akl[c_local] = k;
            if (nq == 0) { ws[WS_AQ + cg] = a; ws[WS_AK + cg] = k; }
        }
    }
    __syncthreads();
    const int col = t & 63, grp = t >> 6;
    const int n = nq * 64 + col;
    const float* xb = x + ((size_t)b * NC + ch * 128 + grp * 32) * NN + n;
    const float* ub = u + ((size_t)b * NC + ch * 128 + grp * 32) * NN + n;
    float eqp = 0.f, ekp = 0.f, map = 0.f, mkp = 0.f;
#pragma unroll 8
    for (int i = 0; i < 32; ++i) {
        float xv = xb[(size_t)i * NN];
        float uv = ub[(size_t)i * NN];
        float a = aql[grp * 32 + i], kk = akl[grp * 32 + i];
        eqp += a * xv; ekp += kk * xv;
        map += a * uv; mkp += kk * uv;
    }
    red[grp][0][col] = eqp; red[grp][1][col] = ekp;
    red[grp][2][col] = map; red[grp][3][col] = mkp;
    __syncthreads();
    if (t < 64) {
        int idx = (b * 2 + ch) * 1024 + nq * 64 + t;
        ws[WS_EQP2  + idx] = red[0][0][t] + red[1][0][t] + red[2][0][t] + red[3][0][t];
        ws[WS_EKP2  + idx] = red[0][1][t] + red[1][1][t] + red[2][1][t] + red[3][1][t];
        ws[WS_MAQP2 + idx] = red[0][2][t] + red[1][2][t] + red[2][2][t] + red[3][2][t];
        ws[WS_MAKP2 + idx] = red[0][3][t] + red[1][3][t] + red[2][3][t] + red[3][3][t];
    }
}

// kB: finalize eq/ek/maq/mak (2 partials in-register), moments, row-dots.
__global__ void kB(const float* __restrict__ x, const float* __restrict__ u,
                   const float* __restrict__ Wc, const float* __restrict__ bq,
                   const float* __restrict__ bk, float* __restrict__ ws) {
    const int bid = blockIdx.x;
    const int b = bid >> 5, g = bid & 31;
    const int c0 = g * 8;
    const int t = threadIdx.x;   // 256
    const int wid = t >> 6, lane = t & 63;
    __shared__ float s_cq, s_ck;
    __shared__ float mred[4][4];
    __shared__ float wv9[8][9][4];
    __shared__ float accw[2][4];
    if (t < 64) {
        float p = Wc[t] * bq[t], rr = Wc[64 + t] * bk[t];
        for (int off = 32; off > 0; off >>= 1) {
            p += __shfl_down(p, off, 64);
            rr += __shfl_down(rr, off, 64);
        }
        if (t == 0) { s_cq = p; s_ck = rr; }
    }
    __syncthreads();
    const float cq = s_cq, ck = s_ck;
    float4 e4, k4, ma4, mk4;
    {
        float4 a0 = ((const float4*)(ws + WS_EQP2 + (size_t)(b * 2) * 1024))[t];
        float4 a1 = ((const float4*)(ws + WS_EQP2 + (size_t)(b * 2 + 1) * 1024))[t];
        e4.x = a0.x + a1.x + cq; e4.y = a0.y + a1.y + cq;
        e4.z = a0.z + a1.z + cq; e4.w = a0.w + a1.w + cq;
        a0 = ((const float4*)(ws + WS_EKP2 + (size_t)(b * 2) * 1024))[t];
        a1 = ((const float4*)(ws + WS_EKP2 + (size_t)(b * 2 + 1) * 1024))[t];
        k4.x = a0.x + a1.x + ck; k4.y = a0.y + a1.y + ck;
        k4.z = a0.z + a1.z + ck; k4.w = a0.w + a1.w + ck;
        a0 = ((const float4*)(ws + WS_MAQP2 + (size_t)(b * 2) * 1024))[t];
        a1 = ((const float4*)(ws + WS_MAQP2 + (size_t)(b * 2 + 1) * 1024))[t];
        ma4.x = a0.x + a1.x; ma4.y = a0.y + a1.y; ma4.z = a0.z + a1.z; ma4.w = a0.w + a1.w;
        a0 = ((const float4*)(ws + WS_MAKP2 + (size_t)(b * 2) * 1024))[t];
        a1 = ((const float4*)(ws + WS_MAKP2 + (size_t)(b * 2 + 1) * 1024))[t];
        mk4.x = a0.x + a1.x; mk4.y = a0.y + a1.y; mk4.z = a0.z + a1.z; mk4.w = a0.w + a1.w;
    }
    {
        float d0 = sum4(e4), d1 = sum4(k4), d2 = dot4(k4, k4), d3 = dot4(e4, k4);
        for (int off = 32; off > 0; off >>= 1) {
            d0 += __shfl_down(d0, off, 64);
            d1 += __shfl_down(d1, off, 64);
            d2 += __shfl_down(d2, off, 64);
            d3 += __shfl_down(d3, off, 64);
        }
        if (lane == 0) { mred[0][wid] = d0; mred[1][wid] = d1; mred[2][wid] = d2; mred[3][wid] = d3; }
    }
    __syncthreads();
    if (t == 0)
        for (int m = 0; m < 4; ++m)
            ws[WS_MOM2 + b * 4 + m] = mred[m][0] + mred[m][1] + mred[m][2] + mred[m][3];
    if (g == 0)
        ((float4*)(ws + WS_STAT + b * STAT_STRIDE + ST_EK))[t] = k4;
    const float4* xb4 = (const float4*)(x + ((size_t)b * NC + c0) * NN);
    const float4* ub4 = (const float4*)(u + ((size_t)b * NC + c0) * NN);
    float x2a = 0.f, uua = 0.f;
#pragma unroll
    for (int c = 0; c < 8; ++c) {
        float4 xv = xb4[c * 256 + t];
        float4 uv = ub4[c * 256 + t];
        float d[9];
        d[0] = dot4(xv, e4);   // xe
        d[1] = dot4(xv, k4);   // xk
        d[2] = sum4(uv);       // Vsu
        d[3] = dot4(uv, e4);   // Ue
        d[4] = dot4(uv, k4);   // Veu
        d[5] = dot4(xv, ma4);  // caq
        d[6] = dot4(xv, mk4);  // cak
        d[7] = dot4(uv, mk4);  // cuak
        d[8] = sum4(xv);       // sx
        x2a += dot4(xv, xv);
        uua += dot4(uv, uv);
        for (int off = 32; off > 0; off >>= 1)
            for (int m = 0; m < 9; ++m) d[m] += __shfl_down(d[m], off, 64);
        if (lane == 0) for (int m = 0; m < 9; ++m) wv9[c][m][wid] = d[m];
    }
    for (int off = 32; off > 0; off >>= 1) {
        x2a += __shfl_down(x2a, off, 64);
        uua += __shfl_down(uua, off, 64);
    }
    if (lane == 0) { accw[0][wid] = x2a; accw[1][wid] = uua; }
    __syncthreads();
    if (t < 8) {
        int c = t;
        float v[9];
        for (int m = 0; m < 9; ++m)
            v[m] = wv9[c][m][0] + wv9[c][m][1] + wv9[c][m][2] + wv9[c][m][3];
        ws[WS_XE   + b * NC + c0 + c] = v[0];
        ws[WS_XK   + b * NC + c0 + c] = v[1];
        ws[WS_VSU  + b * NC + c0 + c] = v[2];
        ws[WS_UE   + b * NC + c0 + c] = v[3];
        ws[WS_VEU  + b * NC + c0 + c] = v[4];
        ws[WS_CAQ  + b * NC + c0 + c] = v[5];
        ws[WS_CAK  + b * NC + c0 + c] = v[6];
        ws[WS_CUAK + b * NC + c0 + c] = v[7];
        ws[WS_SX   + b * NC + c0 + c] = v[8];
    }
    if (t == 0) {
        ws[WS_SX2P + bid] = accw[0][0] + accw[0][1] + accw[0][2] + accw[0][3];
        ws[WS_UUP + bid]  = accw[1][0] + accw[1][1] + accw[1][2] + accw[1][3];
    }
}

// ksv: Sv/Sve matvec + per-block T1/T2 partials for d2
__global__ void ksv(const float* __restrict__ Wv, const float* __restrict__ bv,
                    const float* __restrict__ Wc, const float* __restrict__ bq,
                    const float* __restrict__ bk, float* __restrict__ ws) {
    const int bid = blockIdx.x;          // 64: b*8 + oc
    const int b = bid >> 3, oc = bid & 7;
    const int t = threadIdx.x;           // 256
    const int o_sub = t >> 3, ks = t & 7;
    const int o = oc * 32 + o_sub;
    __shared__ float sxl[NC], xel[NC];
    __shared__ float T1s[32], T2s[32];
    __shared__ float s_cq, s_ck;
    if (t < 64) {
        float p = Wc[t] * bq[t], rr = Wc[64 + t] * bk[t];
        for (int off = 32; off > 0; off >>= 1) {
            p += __shfl_down(p, off, 64);
            rr += __shfl_down(rr, off, 64);
        }
        if (t == 0) { s_cq = p; s_ck = rr; }
    }
    sxl[t] = ws[WS_SX + b * NC + t];
    xel[t] = ws[WS_XE + b * NC + t];
    __syncthreads();
    const float Seq  = ws[WS_MOM2 + b * 4 + 0];
    const float Sek  = ws[WS_MOM2 + b * 4 + 1];
    const float Sek2 = ws[WS_MOM2 + b * 4 + 2];
    const float cq = s_cq, ck = s_ck;
    float wsx = 0.f, wxe = 0.f;
    const float4* wrow = (const float4*)(Wv + (size_t)o * NC);
#pragma unroll
    for (int i = 0; i < 8; ++i) {
        float4 w4 = wrow[i * 8 + ks];
        int k = i * 32 + ks * 4;
        wsx += w4.x * sxl[k] + w4.y * sxl[k + 1] + w4.z * sxl[k + 2] + w4.w * sxl[k + 3];
        wxe += w4.x * xel[k] + w4.y * xel[k + 1] + w4.z * xel[k + 2] + w4.w * xel[k + 3];
    }
    for (int off = 4; off > 0; off >>= 1) {
        wsx += __shfl_down(wsx, off, 8);
        wxe += __shfl_down(wxe, off, 8);
    }
    if (ks == 0) {
        float bvc = bv[o];
        float Sv  = wsx + (float)NN * bvc;
        float SvL = wsx;
        float Sve = wxe + bvc * Seq;
        float* st = ws + WS_STAT + b * STAT_STRIDE;
        st[ST_SV + o] = Sv; st[ST_SVE + o] = Sve;
        float A = 2.f * Sve - bvc * Seq - cq * Sv;
        float sx = sxl[o];
        float xk = ws[WS_XK + b * NC + o];
        float xkL = xk - ck * sx;
        float T1c = A * sx + Sv * xkL + SvL * xk;
        float SP  = Sek - (float)NN * ck;
        float SP2 = Sek2 - 2.f * ck * Sek + (float)NN * ck * ck;
        float SPQ = Sek2 - ck * Sek;
        float T2c = (float)NN * A * A + Sv * Sv * SP2 + SvL * SvL * Sek2
                  + 2.f * A * Sv * SP + 2.f * A * SvL * Sek + 2.f * Sv * SvL * SPQ;
        T1s[o_sub] = T1c; T2s[o_sub] = T2c;
    }
    __syncthreads();
    if (t == 0) {
        float t1 = 0.f, t2 = 0.f;
        for (int i = 0; i < 32; ++i) { t1 += T1s[i]; t2 += T2s[i]; }
        ws[WS_T1P + bid] = t1;
        ws[WS_T2P + bid] = t2;
    }
}

// kfin: blocks 0..7 = vjp/trace recursion; blocks 8..519 = output-0 stream
// (runs on the other CUs concurrently — r10-measured fusion).
// __launch_bounds__(1024,4): a 1024-thread/137KB block IS 4 waves/EU, so the
// legal VGPR budget is 128 (compiler default capped at 64 and serialized the
// LDS reads — r13's 41.6us). Inner loop: W b32 conflict-free + VV uint4
// uniform (48 LDS instrs/thread/iter vs 64), batched in named registers.
struct KFSMem {
    unsigned int Wlds[32768];              // 128KB packed bf16 pairs
    unsigned int VVb[NC] __attribute__((aligned(16)));
    float redPR[2048];
    float dred[9][4];
    float gred0[4];
    float gredT[2];
    float sge;
};

__global__ void __launch_bounds__(1024, 4) kfin(
        const float* __restrict__ x, const float* __restrict__ bv,
        const float* __restrict__ gamma, float* __restrict__ ws,
        float* __restrict__ out) {
    __shared__ __align__(16) unsigned char smem_raw[sizeof(KFSMem)];
    KFSMem& S = *(KFSMem*)smem_raw;
    const int bid = blockIdx.x;      // 520
    const int t = threadIdx.x;       // 1024
    const int lane = t & 63;
    const bool is_iter = (bid < 8);
    // stage WVB loads early (kiter blocks only) — hide under gamma reduce
    uint4 stg0, stg1, stg2, stg3, stg4, stg5, stg6, stg7;
    if (is_iter) {
        const uint4* wvb4 = (const uint4*)((const unsigned int*)ws + WS_WVB);
        stg0 = wvb4[0 * 1024 + t]; stg1 = wvb4[1 * 1024 + t];
        stg2 = wvb4[2 * 1024 + t]; stg3 = wvb4[3 * 1024 + t];
        stg4 = wvb4[4 * 1024 + t]; stg5 = wvb4[5 * 1024 + t];
        stg6 = wvb4[6 * 1024 + t]; stg7 = wvb4[7 * 1024 + t];
    }
    // gamma_eff (all blocks; deterministic)
    {
        float a = 0.f, b1 = 0.f, c1 = 0.f;
        if (t < 256) a = ws[WS_SX2P + t];
        if (t < 64) { b1 = ws[WS_T1P + t]; c1 = ws[WS_T2P + t]; }
        for (int off = 32; off > 0; off >>= 1) {
            a  += __shfl_down(a,  off, 64);
            b1 += __shfl_down(b1, off, 64);
            c1 += __shfl_down(c1, off, 64);
        }
        if (t < 256 && lane == 0) S.gred0[t >> 6] = a;
        if (t == 0) { S.gredT[0] = b1; S.gredT[1] = c1; }
    }
    __syncthreads();
    if (t == 0) {
        float S1 = S.gred0[0] + S.gred0[1] + S.gred0[2] + S.gred0[3];
        float inv = gamma[0] * (1.f / (float)NN);
        float dd = S1 + 2.f * inv * S.gredT[0] + inv * inv * S.gredT[1];
        float lip = sqrtf(dd / S1);
        S.sge = gamma[0] * ((lip > 0.9f) ? (0.9f / lip) : 1.f);
    }
    __syncthreads();
    const float ge = S.sge;

    if (!is_iter) {
        // ---------------- output-0: 4 rows of 1024 per block ----------------
        const float gn = ge * (1.f / (float)NN);
        const int r = t >> 8, tc = t & 255;
        const int bid2 = (bid - 8) * 4 + r;
        const int b = bid2 >> 8, c = bid2 & 255;
        const float* st = ws + WS_STAT + b * STAT_STRIDE;
        float sv = st[ST_SV + c], sve = st[ST_SVE + c];
        float4 ek4 = ((const float4*)(st + ST_EK))[tc];
        size_t i4 = (size_t)bid2 * 256 + tc;
        float4 x4 = ((const float4*)x)[i4];
        float4 o;
        o.x = 2.f * x4.x + gn * (sve + ek4.x * sv);
        o.y = 2.f * x4.y + gn * (sve + ek4.y * sv);
        o.z = 2.f * x4.z + gn * (sve + ek4.z * sv);
        o.w = 2.f * x4.w + gn * (sve + ek4.w * sv);
        ((float4*)out)[i4] = o;
        return;
    }

    // ---------------- recursion blocks ----------------
    const int b = bid;
    const int o = t & 255, q = t >> 8;
    const int wid4 = o >> 6;
    // write staged W to LDS
    ((uint4*)S.Wlds)[0 * 1024 + t] = stg0; ((uint4*)S.Wlds)[1 * 1024 + t] = stg1;
    ((uint4*)S.Wlds)[2 * 1024 + t] = stg2; ((uint4*)S.Wlds)[3 * 1024 + t] = stg3;
    ((uint4*)S.Wlds)[4 * 1024 + t] = stg4; ((uint4*)S.Wlds)[5 * 1024 + t] = stg5;
    ((uint4*)S.Wlds)[6 * 1024 + t] = stg6; ((uint4*)S.Wlds)[7 * 1024 + t] = stg7;
    const float s = ge * (1.f / (float)NN);
    float Svl_r = 0.f, sxl_r = 0.f, xkl_r = 0.f, caql_r = 0.f, cakl_r = 0.f,
          Uel_r = 0.f, Vsul_r = 0.f, bvl_r = 0.f, aql_r = 0.f, akl_r = 0.f,
          veu_r = 0.f, cuak_r = 0.f, vsreg = 0.f, vereg = 0.f;
    if (t < 256) {
        const float* st = ws + WS_STAT + b * STAT_STRIDE;
        Svl_r  = st[ST_SV + t];
        sxl_r  = ws[WS_SX   + b * NC + t];
        xkl_r  = ws[WS_XK   + b * NC + t];
        caql_r = ws[WS_CAQ  + b * NC + t];
        cakl_r = ws[WS_CAK  + b * NC + t];
        Uel_r  = ws[WS_UE   + b * NC + t];
        Vsul_r = ws[WS_VSU  + b * NC + t];
        veu_r  = ws[WS_VEU  + b * NC + t];
        cuak_r = ws[WS_CUAK + b * NC + t];
        aql_r  = ws[WS_AQ + t];
        akl_r  = ws[WS_AK + t];
        bvl_r  = bv[t];
        vsreg = Vsul_r; vereg = veu_r;
        S.VVb[t] = bf16lo(vsreg) | bf16hi(vereg);
    }
    const float Seq  = ws[WS_MOM2 + b * 4 + 0];
    const float Sek  = ws[WS_MOM2 + b * 4 + 1];
    const float Sekq = ws[WS_MOM2 + b * 4 + 3];
    float uu = 0.f;
    for (int g = 0; g < 32; ++g) uu += ws[WS_UUP + b * 32 + g];
    __syncthreads();
    // prologue dots
    if (t < 256) {
        float d[8] = {Svl_r * cuak_r, aql_r * Vsul_r, akl_r * Vsul_r, akl_r * Uel_r,
                      Svl_r * Vsul_r, Svl_r * veu_r,  Svl_r * aql_r,  Svl_r * akl_r};
        for (int off = 32; off > 0; off >>= 1)
            for (int m = 0; m < 8; ++m) d[m] += __shfl_down(d[m], off, 64);
        if (lane == 0) for (int m = 0; m < 8; ++m) S.dred[m][wid4] = d[m];
    }
    __syncthreads();
    float g2a = 0.f, aqVsu = 0.f, akVsu = 0.f, akUe = 0.f, SvVsu = 0.f, SvVeu = 0.f,
          Svaq = 0.f, Svak = 0.f;
    if (t < 256) {
        g2a   = S.dred[0][0] + S.dred[0][1] + S.dred[0][2] + S.dred[0][3];
        aqVsu = S.dred[1][0] + S.dred[1][1] + S.dred[1][2] + S.dred[1][3];
        akVsu = S.dred[2][0] + S.dred[2][1] + S.dred[2][2] + S.dred[2][3];
        akUe  = S.dred[3][0] + S.dred[3][1] + S.dred[3][2] + S.dred[3][3];
        SvVsu = S.dred[4][0] + S.dred[4][1] + S.dred[4][2] + S.dred[4][3];
        SvVeu = S.dred[5][0] + S.dred[5][1] + S.dred[5][2] + S.dred[5][3];
        Svaq  = S.dred[6][0] + S.dred[6][1] + S.dred[6][2] + S.dred[6][3];
        Svak  = S.dred[7][0] + S.dred[7][1] + S.dred[7][2] + S.dred[7][3];
    }
    __syncthreads();
    const float lam = 1.f + s * Svak;
    float alpha = 1.f, beta = 0.f, gam = 0.f;
    float SxAcc = 0.f, XkAcc = 0.f, CakAcc = 0.f;
    float dot = uu, tr = 0.f;
    const float coef[5] = {1.f, -0.5f, 1.f / 3.f, -0.25f, 0.2f};
    for (int j = 0; j < 5; ++j) {
        // matvec: W b32 (conflict-free) + VV uint4 uniform broadcasts, batched
        float pa = 0.f, ra = 0.f;
#pragma unroll
        for (int kk = 0; kk < 8; ++kk) {
            const int base = (q * 32 + 4 * kk) * 256 + o;
            unsigned int w0 = S.Wlds[base];
            unsigned int w1 = S.Wlds[base + 256];
            unsigned int w2 = S.Wlds[base + 512];
            unsigned int w3 = S.Wlds[base + 768];
            uint4 va = ((const uint4*)S.VVb)[q * 16 + 2 * kk];
            uint4 vb = ((const uint4*)S.VVb)[q * 16 + 2 * kk + 1];
            pa += tolo(w0) * tolo(va.x) + tohi(w0) * tolo(va.y);
            ra += tolo(w0) * tohi(va.x) + tohi(w0) * tohi(va.y);
            pa += tolo(w1) * tolo(va.z) + tohi(w1) * tolo(va.w);
            ra += tolo(w1) * tohi(va.z) + tohi(w1) * tohi(va.w);
            pa += tolo(w2) * tolo(vb.x) + tohi(w2) * tolo(vb.y);
            ra += tolo(w2) * tohi(vb.x) + tohi(w2) * tohi(vb.y);
            pa += tolo(w3) * tolo(vb.z) + tohi(w3) * tolo(vb.w);
            ra += tolo(w3) * tohi(vb.z) + tohi(w3) * tohi(vb.w);
        }
        S.redPR[2 * t] = pa; S.redPR[2 * t + 1] = ra;
        __syncthreads();
        if (t < 256) {
            float Pv = s * (S.redPR[2 * t] + S.redPR[2 * (t + 256)] + S.redPR[2 * (t + 512)] + S.redPR[2 * (t + 768)]);
            float Rv = s * (S.redPR[2 * t + 1] + S.redPR[2 * (t + 256) + 1] + S.redPR[2 * (t + 512) + 1] + S.redPR[2 * (t + 768) + 1]);
            float d[9];
            d[0] = Svl_r * Pv;
            d[1] = Svl_r * Rv;
            d[2] = bvl_r * vsreg;
            d[3] = sxl_r * Pv;
            d[4] = xkl_r * Pv;
            d[5] = caql_r * Pv;
            d[6] = cakl_r * Pv;
            d[7] = Uel_r * Pv;
            d[8] = Vsul_r * Rv;
            for (int off = 32; off > 0; off >>= 1)
                for (int m = 0; m < 9; ++m) d[m] += __shfl_down(d[m], off, 64);
            if (lane == 0) for (int m = 0; m < 9; ++m) S.dred[m][wid4] = d[m];
            __syncthreads();
            float sm[9];
            for (int m = 0; m < 9; ++m)
                sm[m] = S.dred[m][0] + S.dred[m][1] + S.dred[m][2] + S.dred[m][3];
            const float svP = sm[0], svR = sm[1], bvVs = sm[2], sxP = sm[3], xkP = sm[4],
                        caqP = sm[5], cakP = sm[6], ueP = sm[7], vsuR = sm[8];
            const float sB = s * bvVs;
            float St  = s * (alpha * SvVsu + beta * (float)NN + gam * Seq  + Svaq * SxAcc);
            float tek = s * (alpha * SvVeu + beta * Sek        + gam * Sekq + Svaq * XkAcc);
            float uta = s * (alpha * g2a   + beta * akVsu      + gam * akUe + Svaq * CakAcc);
            dot += ueP + caqP + sB * aqVsu + uta + vsuR;
            tr  += coef[j] * dot;
            float nVs = vsreg + Pv * Seq  + aql_r * (sxP + (float)NN * sB) + akl_r * St  + Rv * (float)NN;
            float nVe = vereg + Pv * Sekq + aql_r * (xkP + sB * Sek)       + akl_r * tek + Rv * Sek;
            vsreg = nVs; vereg = nVe;
            S.VVb[t] = bf16lo(nVs) | bf16hi(nVe);
            SxAcc  = lam * SxAcc  + sxP;
            XkAcc  = lam * XkAcc  + xkP;
            CakAcc = lam * CakAcc + cakP;
            beta = lam * beta + Svaq * sB + svR;
            gam  = lam * gam + svP;
            alpha *= lam;
        } else {
            __syncthreads();
        }
        __syncthreads();
    }
    if (t == 0) out[2097152 + b] = tr;
}

extern "C" void kernel_launch(void* const* d_in, const int* in_sizes, int n_in,
                              void* d_out, int out_size, void* d_ws, size_t ws_size,
                              hipStream_t stream) {
    const float* x     = (const float*)d_in[0];
    const float* Wq    = (const float*)d_in[1];
    const float* bq    = (const float*)d_in[2];
    const float* Wk    = (const float*)d_in[3];
    const float* bk    = (const float*)d_in[4];
    const float* Wc    = (const float*)d_in[5];
    const float* Wv    = (const float*)d_in[6];
    const float* bv    = (const float*)d_in[7];
    const float* gamma = (const float*)d_in[8];
    const float* u     = (const float*)d_in[9];
    float* out = (float*)d_out;
    float* ws  = (float*)d_ws;

    kA  <<<dim3(288), dim3(256),  0, stream>>>(x, u, Wq, Wk, Wc, Wv, ws);
    kB  <<<dim3(256), dim3(256),  0, stream>>>(x, u, Wc, bq, bk, ws);
    ksv <<<dim3(64),  dim3(256),  0, stream>>>(Wv, bv, Wc, bq, bk, ws);
    kfin<<<dim3(520), dim3(1024), 0, stream>>>(x, bv, gamma, ws, out);
}

// Round 15
// 46.160 us; speedup vs baseline: 2.3616x; 1.2019x over previous
//
#include <hip/hip_runtime.h>
#include <math.h>

// Problem constants
#define NB 8      // batch
#define NC 256    // channels
#define NN 1024   // spatial H*W
#define NICH 64   // inter channels

// ws layout (float offsets)
#define WS_AQ    0        // [256]
#define WS_AK    256      // [256]
#define WS_MOM2  520      // [8][4]: Seq,Sek,Sek2,Sekq per batch
#define WS_SX    1024     // [8][256]
#define WS_XE    3072     // [8][256]
#define WS_XK    5120     // [8][256]
#define WS_T1P   7424     // [64]
#define WS_T2P   7488     // [64]
#define WS_VSU   7680     // [8][256]
#define WS_UE    9728     // [8][256]
#define WS_VEU   11776    // [8][256]
#define WS_CAQ   13824    // [8][256]
#define WS_CAK   15872    // [8][256]
#define WS_CUAK  17920    // [8][256]
#define WS_STAT  20480    // [8] stride 2560: (ek, Sv, Sve used)
#define STAT_STRIDE 2560
#define ST_EK    1024
#define ST_SV    2048
#define ST_SVE   2304
#define WS_EQP2  57344    // [16][1024] depth-2 partials (b*2+ch)
#define WS_EKP2  73728    // [16][1024]
#define WS_MAQP2 90112    // [16][1024]
#define WS_MAKP2 106496   // [16][1024]
#define WS_SX2P  123904   // [256]
#define WS_UUP   124160   // [256]
#define WS_WVB   124416   // [32768] u32: W^T bf16 pairs, swizzled MFMA-B layout

typedef short bf16x8 __attribute__((ext_vector_type(8)));
typedef float f32x4 __attribute__((ext_vector_type(4)));
union FragU { uint4 u; bf16x8 h; };

__device__ __forceinline__ float dot4(const float4& a, const float4& b) {
    return a.x * b.x + a.y * b.y + a.z * b.z + a.w * b.w;
}
__device__ __forceinline__ float sum4(const float4& a) {
    return a.x + a.y + a.z + a.w;
}
__device__ __forceinline__ unsigned int bf16lo(float v) {
    unsigned int u = __float_as_uint(v);
    return (u + 0x7FFFu + ((u >> 16) & 1u)) >> 16;
}
__device__ __forceinline__ unsigned int bf16hi(float v) {
    unsigned int u = __float_as_uint(v);
    return (u + 0x7FFFu + ((u >> 16) & 1u)) & 0xFFFF0000u;
}

// kA: depth-2 partials of eq/ek/maq/mak (blocks 0..255) + W^T bf16 MFMA-B
// conversion via LDS tile transpose (blocks 256..259, each a 64-o stripe).
// Storage: WVB_u4[o*32 + s] = logical uint4 group g = s ^ (o&7) of row o,
// covering channels 8g..8g+7 as bf16 pairs (elem 2i low half of u32 i).
__global__ void kA(const float* __restrict__ x, const float* __restrict__ u,
                   const float* __restrict__ Wq, const float* __restrict__ Wk,
                   const float* __restrict__ Wc, const float* __restrict__ Wv,
                   float* __restrict__ ws) {
    const int bid = blockIdx.x;
    const int t = threadIdx.x;   // 256
    __shared__ float tile[256][65];   // transpose tile (65 = +1 pad)
    __shared__ float aql[128], akl[128];
    __shared__ float red[4][4][64];
    if (bid >= 256) {
        const int o0 = (bid - 256) * 64;
        // load: 4 ch-rows x 64 o per pass, coalesced
        const int cho = t >> 6, ol = t & 63;
#pragma unroll 8
        for (int p = 0; p < 64; ++p) {
            int ch = p * 4 + cho;
            tile[ch][ol] = Wv[(size_t)ch * NC + o0 + ol];
        }
        __syncthreads();
        uint4* wvb4 = (uint4*)((unsigned int*)ws + WS_WVB);
#pragma unroll
        for (int i = 0; i < 8; ++i) {
            int idx = i * 256 + t;
            int o_l = idx >> 5, s = idx & 31;
            int o = o0 + o_l;
            int g = s ^ (o & 7);
            uint4 out;
            out.x = bf16lo(tile[8 * g + 0][o_l]) | bf16hi(tile[8 * g + 1][o_l]);
            out.y = bf16lo(tile[8 * g + 2][o_l]) | bf16hi(tile[8 * g + 3][o_l]);
            out.z = bf16lo(tile[8 * g + 4][o_l]) | bf16hi(tile[8 * g + 5][o_l]);
            out.w = bf16lo(tile[8 * g + 6][o_l]) | bf16hi(tile[8 * g + 7][o_l]);
            wvb4[(size_t)(bid - 256) * 2048 + idx] = out;
        }
        return;
    }
    const int b = bid >> 5, r = bid & 31;
    const int nq = r >> 1, ch = r & 1;
    {
        const int c_local = t >> 1, half = t & 1;
        const int cg = ch * 128 + c_local;
        float a = 0.f, k = 0.f;
#pragma unroll 8
        for (int i = 0; i < 32; ++i) {
            int o = half * 32 + i;
            a += Wc[o] * Wq[o * NC + cg];
            k += Wc[64 + o] * Wk[o * NC + cg];
        }
        a += __shfl_xor(a, 1, 64);
        k += __shfl_xor(k, 1, 64);
        if (half == 0) {
            aql[c_local] = a; akl[c_local] = k;
            if (nq == 0) { ws[WS_AQ + cg] = a; ws[WS_AK + cg] = k; }
        }
    }
    __syncthreads();
    const int col = t & 63, grp = t >> 6;
    const int n = nq * 64 + col;
    const float* xb = x + ((size_t)b * NC + ch * 128 + grp * 32) * NN + n;
    const float* ub = u + ((size_t)b * NC + ch * 128 + grp * 32) * NN + n;
    float eqp = 0.f, ekp = 0.f, map = 0.f, mkp = 0.f;
#pragma unroll 8
    for (int i = 0; i < 32; ++i) {
        float xv = xb[(size_t)i * NN];
        float uv = ub[(size_t)i * NN];
        float a = aql[grp * 32 + i], kk = akl[grp * 32 + i];
        eqp += a * xv; ekp += kk * xv;
        map += a * uv; mkp += kk * uv;
    }
    red[grp][0][col] = eqp; red[grp][1][col] = ekp;
    red[grp][2][col] = map; red[grp][3][col] = mkp;
    __syncthreads();
    if (t < 64) {
        int idx = (b * 2 + ch) * 1024 + nq * 64 + t;
        ws[WS_EQP2  + idx] = red[0][0][t] + red[1][0][t] + red[2][0][t] + red[3][0][t];
        ws[WS_EKP2  + idx] = red[0][1][t] + red[1][1][t] + red[2][1][t] + red[3][1][t];
        ws[WS_MAQP2 + idx] = red[0][2][t] + red[1][2][t] + red[2][2][t] + red[3][2][t];
        ws[WS_MAKP2 + idx] = red[0][3][t] + red[1][3][t] + red[2][3][t] + red[3][3][t];
    }
}

// kB: finalize eq/ek/maq/mak (2 partials in-register), moments, row-dots.
__global__ void kB(const float* __restrict__ x, const float* __restrict__ u,
                   const float* __restrict__ Wc, const float* __restrict__ bq,
                   const float* __restrict__ bk, float* __restrict__ ws) {
    const int bid = blockIdx.x;
    const int b = bid >> 5, g = bid & 31;
    const int c0 = g * 8;
    const int t = threadIdx.x;   // 256
    const int wid = t >> 6, lane = t & 63;
    __shared__ float s_cq, s_ck;
    __shared__ float mred[4][4];
    __shared__ float wv9[8][9][4];
    __shared__ float accw[2][4];
    if (t < 64) {
        float p = Wc[t] * bq[t], rr = Wc[64 + t] * bk[t];
        for (int off = 32; off > 0; off >>= 1) {
            p += __shfl_down(p, off, 64);
            rr += __shfl_down(rr, off, 64);
        }
        if (t == 0) { s_cq = p; s_ck = rr; }
    }
    __syncthreads();
    const float cq = s_cq, ck = s_ck;
    float4 e4, k4, ma4, mk4;
    {
        float4 a0 = ((const float4*)(ws + WS_EQP2 + (size_t)(b * 2) * 1024))[t];
        float4 a1 = ((const float4*)(ws + WS_EQP2 + (size_t)(b * 2 + 1) * 1024))[t];
        e4.x = a0.x + a1.x + cq; e4.y = a0.y + a1.y + cq;
        e4.z = a0.z + a1.z + cq; e4.w = a0.w + a1.w + cq;
        a0 = ((const float4*)(ws + WS_EKP2 + (size_t)(b * 2) * 1024))[t];
        a1 = ((const float4*)(ws + WS_EKP2 + (size_t)(b * 2 + 1) * 1024))[t];
        k4.x = a0.x + a1.x + ck; k4.y = a0.y + a1.y + ck;
        k4.z = a0.z + a1.z + ck; k4.w = a0.w + a1.w + ck;
        a0 = ((const float4*)(ws + WS_MAQP2 + (size_t)(b * 2) * 1024))[t];
        a1 = ((const float4*)(ws + WS_MAQP2 + (size_t)(b * 2 + 1) * 1024))[t];
        ma4.x = a0.x + a1.x; ma4.y = a0.y + a1.y; ma4.z = a0.z + a1.z; ma4.w = a0.w + a1.w;
        a0 = ((const float4*)(ws + WS_MAKP2 + (size_t)(b * 2) * 1024))[t];
        a1 = ((const float4*)(ws + WS_MAKP2 + (size_t)(b * 2 + 1) * 1024))[t];
        mk4.x = a0.x + a1.x; mk4.y = a0.y + a1.y; mk4.z = a0.z + a1.z; mk4.w = a0.w + a1.w;
    }
    {
        float d0 = sum4(e4), d1 = sum4(k4), d2 = dot4(k4, k4), d3 = dot4(e4, k4);
        for (int off = 32; off > 0; off >>= 1) {
            d0 += __shfl_down(d0, off, 64);
            d1 += __shfl_down(d1, off, 64);
            d2 += __shfl_down(d2, off, 64);
            d3 += __shfl_down(d3, off, 64);
        }
        if (lane == 0) { mred[0][wid] = d0; mred[1][wid] = d1; mred[2][wid] = d2; mred[3][wid] = d3; }
    }
    __syncthreads();
    if (t == 0)
        for (int m = 0; m < 4; ++m)
            ws[WS_MOM2 + b * 4 + m] = mred[m][0] + mred[m][1] + mred[m][2] + mred[m][3];
    if (g == 0)
        ((float4*)(ws + WS_STAT + b * STAT_STRIDE + ST_EK))[t] = k4;
    const float4* xb4 = (const float4*)(x + ((size_t)b * NC + c0) * NN);
    const float4* ub4 = (const float4*)(u + ((size_t)b * NC + c0) * NN);
    float x2a = 0.f, uua = 0.f;
#pragma unroll
    for (int c = 0; c < 8; ++c) {
        float4 xv = xb4[c * 256 + t];
        float4 uv = ub4[c * 256 + t];
        float d[9];
        d[0] = dot4(xv, e4);   // xe
        d[1] = dot4(xv, k4);   // xk
        d[2] = sum4(uv);       // Vsu
        d[3] = dot4(uv, e4);   // Ue
        d[4] = dot4(uv, k4);   // Veu
        d[5] = dot4(xv, ma4);  // caq
        d[6] = dot4(xv, mk4);  // cak
        d[7] = dot4(uv, mk4);  // cuak
        d[8] = sum4(xv);       // sx
        x2a += dot4(xv, xv);
        uua += dot4(uv, uv);
        for (int off = 32; off > 0; off >>= 1)
            for (int m = 0; m < 9; ++m) d[m] += __shfl_down(d[m], off, 64);
        if (lane == 0) for (int m = 0; m < 9; ++m) wv9[c][m][wid] = d[m];
    }
    for (int off = 32; off > 0; off >>= 1) {
        x2a += __shfl_down(x2a, off, 64);
        uua += __shfl_down(uua, off, 64);
    }
    if (lane == 0) { accw[0][wid] = x2a; accw[1][wid] = uua; }
    __syncthreads();
    if (t < 8) {
        int c = t;
        float v[9];
        for (int m = 0; m < 9; ++m)
            v[m] = wv9[c][m][0] + wv9[c][m][1] + wv9[c][m][2] + wv9[c][m][3];
        ws[WS_XE   + b * NC + c0 + c] = v[0];
        ws[WS_XK   + b * NC + c0 + c] = v[1];
        ws[WS_VSU  + b * NC + c0 + c] = v[2];
        ws[WS_UE   + b * NC + c0 + c] = v[3];
        ws[WS_VEU  + b * NC + c0 + c] = v[4];
        ws[WS_CAQ  + b * NC + c0 + c] = v[5];
        ws[WS_CAK  + b * NC + c0 + c] = v[6];
        ws[WS_CUAK + b * NC + c0 + c] = v[7];
        ws[WS_SX   + b * NC + c0 + c] = v[8];
    }
    if (t == 0) {
        ws[WS_SX2P + bid] = accw[0][0] + accw[0][1] + accw[0][2] + accw[0][3];
        ws[WS_UUP + bid]  = accw[1][0] + accw[1][1] + accw[1][2] + accw[1][3];
    }
}

// ksv: Sv/Sve matvec + per-block T1/T2 partials for d2
__global__ void ksv(const float* __restrict__ Wv, const float* __restrict__ bv,
                    const float* __restrict__ Wc, const float* __restrict__ bq,
                    const float* __restrict__ bk, float* __restrict__ ws) {
    const int bid = blockIdx.x;          // 64: b*8 + oc
    const int b = bid >> 3, oc = bid & 7;
    const int t = threadIdx.x;           // 256
    const int o_sub = t >> 3, ks = t & 7;
    const int o = oc * 32 + o_sub;
    __shared__ float sxl[NC], xel[NC];
    __shared__ float T1s[32], T2s[32];
    __shared__ float s_cq, s_ck;
    if (t < 64) {
        float p = Wc[t] * bq[t], rr = Wc[64 + t] * bk[t];
        for (int off = 32; off > 0; off >>= 1) {
            p += __shfl_down(p, off, 64);
            rr += __shfl_down(rr, off, 64);
        }
        if (t == 0) { s_cq = p; s_ck = rr; }
    }
    sxl[t] = ws[WS_SX + b * NC + t];
    xel[t] = ws[WS_XE + b * NC + t];
    __syncthreads();
    const float Seq  = ws[WS_MOM2 + b * 4 + 0];
    const float Sek  = ws[WS_MOM2 + b * 4 + 1];
    const float Sek2 = ws[WS_MOM2 + b * 4 + 2];
    const float cq = s_cq, ck = s_ck;
    float wsx = 0.f, wxe = 0.f;
    const float4* wrow = (const float4*)(Wv + (size_t)o * NC);
#pragma unroll
    for (int i = 0; i < 8; ++i) {
        float4 w4 = wrow[i * 8 + ks];
        int k = i * 32 + ks * 4;
        wsx += w4.x * sxl[k] + w4.y * sxl[k + 1] + w4.z * sxl[k + 2] + w4.w * sxl[k + 3];
        wxe += w4.x * xel[k] + w4.y * xel[k + 1] + w4.z * xel[k + 2] + w4.w * xel[k + 3];
    }
    for (int off = 4; off > 0; off >>= 1) {
        wsx += __shfl_down(wsx, off, 8);
        wxe += __shfl_down(wxe, off, 8);
    }
    if (ks == 0) {
        float bvc = bv[o];
        float Sv  = wsx + (float)NN * bvc;
        float SvL = wsx;
        float Sve = wxe + bvc * Seq;
        float* st = ws + WS_STAT + b * STAT_STRIDE;
        st[ST_SV + o] = Sv; st[ST_SVE + o] = Sve;
        float A = 2.f * Sve - bvc * Seq - cq * Sv;
        float sx = sxl[o];
        float xk = ws[WS_XK + b * NC + o];
        float xkL = xk - ck * sx;
        float T1c = A * sx + Sv * xkL + SvL * xk;
        float SP  = Sek - (float)NN * ck;
        float SP2 = Sek2 - 2.f * ck * Sek + (float)NN * ck * ck;
        float SPQ = Sek2 - ck * Sek;
        float T2c = (float)NN * A * A + Sv * Sv * SP2 + SvL * SvL * Sek2
                  + 2.f * A * Sv * SP + 2.f * A * SvL * Sek + 2.f * Sv * SvL * SPQ;
        T1s[o_sub] = T1c; T2s[o_sub] = T2c;
    }
    __syncthreads();
    if (t == 0) {
        float t1 = 0.f, t2 = 0.f;
        for (int i = 0; i < 32; ++i) { t1 += T1s[i]; t2 += T2s[i]; }
        ws[WS_T1P + bid] = t1;
        ws[WS_T2P + bid] = t2;
    }
}

// kfin: blocks 0..7 = recursion via MFMA; blocks 8..519 = output-0 stream.
// Matvec [P;R] = [Vs;Ve] x W via mfma_f32_16x16x32_bf16: wave nt handles
// output tile nt (cols nt*16..+15), 8 MFMA over K=256. C layout (verified):
// col=lane&15, row=(lane>>4)*4+reg -> P = reg0 lanes 0-15, R = reg1.
// No redPR reduction phase; scalar 9-dot phase unchanged.
struct KFSMem {
    unsigned int Wlds[32768];               // 128KB W^T bf16, swizzled
    unsigned int Vsb[128] __attribute__((aligned(16)));
    unsigned int Veb[128] __attribute__((aligned(16)));
    float P_lds[256];
    float R_lds[256];
    float dred[9][4];
    float gred0[4];
    float gredT[2];
    float sge;
};

__global__ void __launch_bounds__(1024, 4) kfin(
        const float* __restrict__ x, const float* __restrict__ bv,
        const float* __restrict__ gamma, float* __restrict__ ws,
        float* __restrict__ out) {
    __shared__ __align__(16) unsigned char smem_raw[sizeof(KFSMem)];
    KFSMem& S = *(KFSMem*)smem_raw;
    const int bid = blockIdx.x;      // 520
    const int t = threadIdx.x;       // 1024
    const int lane = t & 63;
    const bool is_iter = (bid < 8);
    // stage WVB loads early — hide under gamma reduce
    uint4 stg0, stg1, stg2, stg3, stg4, stg5, stg6, stg7;
    if (is_iter) {
        const uint4* wvb4 = (const uint4*)((const unsigned int*)ws + WS_WVB);
        stg0 = wvb4[0 * 1024 + t]; stg1 = wvb4[1 * 1024 + t];
        stg2 = wvb4[2 * 1024 + t]; stg3 = wvb4[3 * 1024 + t];
        stg4 = wvb4[4 * 1024 + t]; stg5 = wvb4[5 * 1024 + t];
        stg6 = wvb4[6 * 1024 + t]; stg7 = wvb4[7 * 1024 + t];
    }
    // gamma_eff (all blocks; deterministic)
    {
        float a = 0.f, b1 = 0.f, c1 = 0.f;
        if (t < 256) a = ws[WS_SX2P + t];
        if (t < 64) { b1 = ws[WS_T1P + t]; c1 = ws[WS_T2P + t]; }
        for (int off = 32; off > 0; off >>= 1) {
            a  += __shfl_down(a,  off, 64);
            b1 += __shfl_down(b1, off, 64);
            c1 += __shfl_down(c1, off, 64);
        }
        if (t < 256 && lane == 0) S.gred0[t >> 6] = a;
        if (t == 0) { S.gredT[0] = b1; S.gredT[1] = c1; }
    }
    __syncthreads();
    if (t == 0) {
        float S1 = S.gred0[0] + S.gred0[1] + S.gred0[2] + S.gred0[3];
        float inv = gamma[0] * (1.f / (float)NN);
        float dd = S1 + 2.f * inv * S.gredT[0] + inv * inv * S.gredT[1];
        float lip = sqrtf(dd / S1);
        S.sge = gamma[0] * ((lip > 0.9f) ? (0.9f / lip) : 1.f);
    }
    __syncthreads();
    const float ge = S.sge;

    if (!is_iter) {
        // ---------------- output-0: 4 rows of 1024 per block ----------------
        const float gn = ge * (1.f / (float)NN);
        const int r = t >> 8, tc = t & 255;
        const int bid2 = (bid - 8) * 4 + r;
        const int b = bid2 >> 8, c = bid2 & 255;
        const float* st = ws + WS_STAT + b * STAT_STRIDE;
        float sv = st[ST_SV + c], sve = st[ST_SVE + c];
        float4 ek4 = ((const float4*)(st + ST_EK))[tc];
        size_t i4 = (size_t)bid2 * 256 + tc;
        float4 x4 = ((const float4*)x)[i4];
        float4 o;
        o.x = 2.f * x4.x + gn * (sve + ek4.x * sv);
        o.y = 2.f * x4.y + gn * (sve + ek4.y * sv);
        o.z = 2.f * x4.z + gn * (sve + ek4.z * sv);
        o.w = 2.f * x4.w + gn * (sve + ek4.w * sv);
        ((float4*)out)[i4] = o;
        return;
    }

    // ---------------- recursion blocks ----------------
    const int b = bid;
    const int nt = t >> 6;               // wave = output tile 0..15
    const int row = lane & 15;           // M-row within tile (A-row)
    const int kgrp = lane >> 4;          // K-group 0..3
    const int o = nt * 16 + row;         // this lane's output column (B col)
    const int wid4 = (t & 255) >> 6;
    // write staged W to LDS
    ((uint4*)S.Wlds)[0 * 1024 + t] = stg0; ((uint4*)S.Wlds)[1 * 1024 + t] = stg1;
    ((uint4*)S.Wlds)[2 * 1024 + t] = stg2; ((uint4*)S.Wlds)[3 * 1024 + t] = stg3;
    ((uint4*)S.Wlds)[4 * 1024 + t] = stg4; ((uint4*)S.Wlds)[5 * 1024 + t] = stg5;
    ((uint4*)S.Wlds)[6 * 1024 + t] = stg6; ((uint4*)S.Wlds)[7 * 1024 + t] = stg7;
    const float s = ge * (1.f / (float)NN);
    float Svl_r = 0.f, sxl_r = 0.f, xkl_r = 0.f, caql_r = 0.f, cakl_r = 0.f,
          Uel_r = 0.f, Vsul_r = 0.f, bvl_r = 0.f, aql_r = 0.f, akl_r = 0.f,
          veu_r = 0.f, cuak_r = 0.f, vsreg = 0.f, vereg = 0.f;
    if (t < 256) {
        const float* st = ws + WS_STAT + b * STAT_STRIDE;
        Svl_r  = st[ST_SV + t];
        sxl_r  = ws[WS_SX   + b * NC + t];
        xkl_r  = ws[WS_XK   + b * NC + t];
        caql_r = ws[WS_CAQ  + b * NC + t];
        cakl_r = ws[WS_CAK  + b * NC + t];
        Uel_r  = ws[WS_UE   + b * NC + t];
        Vsul_r = ws[WS_VSU  + b * NC + t];
        veu_r  = ws[WS_VEU  + b * NC + t];
        cuak_r = ws[WS_CUAK + b * NC + t];
        aql_r  = ws[WS_AQ + t];
        akl_r  = ws[WS_AK + t];
        bvl_r  = bv[t];
        vsreg = Vsul_r; vereg = veu_r;
        // initial bf16 pack of Vs/Ve via lane-pair shuffle
        float vs_o = __shfl_xor(vsreg, 1, 64);
        float ve_o = __shfl_xor(vereg, 1, 64);
        if ((t & 1) == 0) {
            S.Vsb[t >> 1] = bf16lo(vsreg) | bf16hi(vs_o);
            S.Veb[t >> 1] = bf16lo(vereg) | bf16hi(ve_o);
        }
    }
    const float Seq  = ws[WS_MOM2 + b * 4 + 0];
    const float Sek  = ws[WS_MOM2 + b * 4 + 1];
    const float Sekq = ws[WS_MOM2 + b * 4 + 3];
    float uu = 0.f;
    for (int g = 0; g < 32; ++g) uu += ws[WS_UUP + b * 32 + g];
    __syncthreads();
    // prologue dots
    if (t < 256) {
        float d[8] = {Svl_r * cuak_r, aql_r * Vsul_r, akl_r * Vsul_r, akl_r * Uel_r,
                      Svl_r * Vsul_r, Svl_r * veu_r,  Svl_r * aql_r,  Svl_r * akl_r};
        for (int off = 32; off > 0; off >>= 1)
            for (int m = 0; m < 8; ++m) d[m] += __shfl_down(d[m], off, 64);
        if (lane == 0) for (int m = 0; m < 8; ++m) S.dred[m][wid4] = d[m];
    }
    __syncthreads();
    float g2a = 0.f, aqVsu = 0.f, akVsu = 0.f, akUe = 0.f, SvVsu = 0.f, SvVeu = 0.f,
          Svaq = 0.f, Svak = 0.f;
    if (t < 256) {
        g2a   = S.dred[0][0] + S.dred[0][1] + S.dred[0][2] + S.dred[0][3];
        aqVsu = S.dred[1][0] + S.dred[1][1] + S.dred[1][2] + S.dred[1][3];
        akVsu = S.dred[2][0] + S.dred[2][1] + S.dred[2][2] + S.dred[2][3];
        akUe  = S.dred[3][0] + S.dred[3][1] + S.dred[3][2] + S.dred[3][3];
        SvVsu = S.dred[4][0] + S.dred[4][1] + S.dred[4][2] + S.dred[4][3];
        SvVeu = S.dred[5][0] + S.dred[5][1] + S.dred[5][2] + S.dred[5][3];
        Svaq  = S.dred[6][0] + S.dred[6][1] + S.dred[6][2] + S.dred[6][3];
        Svak  = S.dred[7][0] + S.dred[7][1] + S.dred[7][2] + S.dred[7][3];
    }
    __syncthreads();
    const float lam = 1.f + s * Svak;
    float alpha = 1.f, beta = 0.f, gam = 0.f;
    float SxAcc = 0.f, XkAcc = 0.f, CakAcc = 0.f;
    float dot = uu, tr = 0.f;
    const float coef[5] = {1.f, -0.5f, 1.f / 3.f, -0.25f, 0.2f};
    const uint4* Vsb4 = (const uint4*)S.Vsb;
    const uint4* Veb4 = (const uint4*)S.Veb;
    const uint4* Wlds4 = (const uint4*)S.Wlds;
    for (int j = 0; j < 5; ++j) {
        // MFMA matvec: wave nt computes C[2][16] for its output tile
        f32x4 acc = {0.f, 0.f, 0.f, 0.f};
#pragma unroll
        for (int kc = 0; kc < 8; ++kc) {
            // A-frag: rows 0/1 = Vs/Ve (bf16 pairs), rows >=2 zero
            const uint4* asrc = (row == 1) ? Veb4 : Vsb4;
            uint4 araw = asrc[kc * 4 + kgrp];
            if (row >= 2) { araw.x = 0u; araw.y = 0u; araw.z = 0u; araw.w = 0u; }
            FragU fa; fa.u = araw;
            // B-frag: swizzled W^T, 8 consecutive channels at column o
            FragU fb; fb.u = Wlds4[o * 32 + ((kc * 4 + kgrp) ^ (o & 7))];
            acc = __builtin_amdgcn_mfma_f32_16x16x32_bf16(fa.h, fb.h, acc, 0, 0, 0);
        }
        if (lane < 16) {
            S.P_lds[nt * 16 + lane] = acc[0];   // C row 0 = Vs . W
            S.R_lds[nt * 16 + lane] = acc[1];   // C row 1 = Ve . W
        }
        __syncthreads();
        if (t < 256) {
            float Pv = s * S.P_lds[t];
            float Rv = s * S.R_lds[t];
            float d[9];
            d[0] = Svl_r * Pv;
            d[1] = Svl_r * Rv;
            d[2] = bvl_r * vsreg;
            d[3] = sxl_r * Pv;
            d[4] = xkl_r * Pv;
            d[5] = caql_r * Pv;
            d[6] = cakl_r * Pv;
            d[7] = Uel_r * Pv;
            d[8] = Vsul_r * Rv;
            for (int off = 32; off > 0; off >>= 1)
                for (int m = 0; m < 9; ++m) d[m] += __shfl_down(d[m], off, 64);
            if (lane == 0) for (int m = 0; m < 9; ++m) S.dred[m][wid4] = d[m];
        }
        __syncthreads();
        if (t < 256) {
            float Pv = s * S.P_lds[t];
            float Rv = s * S.R_lds[t];
            float sm[9];
            for (int m = 0; m < 9; ++m)
                sm[m] = S.dred[m][0] + S.dred[m][1] + S.dred[m][2] + S.dred[m][3];
            const float svP = sm[0], svR = sm[1], bvVs = sm[2], sxP = sm[3], xkP = sm[4],
                        caqP = sm[5], cakP = sm[6], ueP = sm[7], vsuR = sm[8];
            const float sB = s * bvVs;
            float St  = s * (alpha * SvVsu + beta * (float)NN + gam * Seq  + Svaq * SxAcc);
            float tek = s * (alpha * SvVeu + beta * Sek        + gam * Sekq + Svaq * XkAcc);
            float uta = s * (alpha * g2a   + beta * akVsu      + gam * akUe + Svaq * CakAcc);
            dot += ueP + caqP + sB * aqVsu + uta + vsuR;
            tr  += coef[j] * dot;
            float nVs = vsreg + Pv * Seq  + aql_r * (sxP + (float)NN * sB) + akl_r * St  + Rv * (float)NN;
            float nVe = vereg + Pv * Sekq + aql_r * (xkP + sB * Sek)       + akl_r * tek + Rv * Sek;
            vsreg = nVs; vereg = nVe;
            // re-pack bf16 Vs/Ve via lane-pair shuffle (no extra barrier)
            float vs_o = __shfl_xor(nVs, 1, 64);
            float ve_o = __shfl_xor(nVe, 1, 64);
            if ((t & 1) == 0) {
                S.Vsb[t >> 1] = bf16lo(nVs) | bf16hi(vs_o);
                S.Veb[t >> 1] = bf16lo(nVe) | bf16hi(ve_o);
            }
            SxAcc  = lam * SxAcc  + sxP;
            XkAcc  = lam * XkAcc  + xkP;
            CakAcc = lam * CakAcc + cakP;
            beta = lam * beta + Svaq * sB + svR;
            gam  = lam * gam + svP;
            alpha *= lam;
        }
        __syncthreads();
    }
    if (t == 0) out[2097152 + b] = tr;
}

extern "C" void kernel_launch(void* const* d_in, const int* in_sizes, int n_in,
                              void* d_out, int out_size, void* d_ws, size_t ws_size,
                              hipStream_t stream) {
    const float* x     = (const float*)d_in[0];
    const float* Wq    = (const float*)d_in[1];
    const float* bq    = (const float*)d_in[2];
    const float* Wk    = (const float*)d_in[3];
    const float* bk    = (const float*)d_in[4];
    const float* Wc    = (const float*)d_in[5];
    const float* Wv    = (const float*)d_in[6];
    const float* bv    = (const float*)d_in[7];
    const float* gamma = (const float*)d_in[8];
    const float* u     = (const float*)d_in[9];
    float* out = (float*)d_out;
    float* ws  = (float*)d_ws;

    kA  <<<dim3(260), dim3(256),  0, stream>>>(x, u, Wq, Wk, Wc, Wv, ws);
    kB  <<<dim3(256), dim3(256),  0, stream>>>(x, u, Wc, bq, bk, ws);
    ksv <<<dim3(64),  dim3(256),  0, stream>>>(Wv, bv, Wc, bq, bk, ws);
    kfin<<<dim3(520), dim3(1024), 0, stream>>>(x, bv, gamma, ws, out);
}